// Round 1
// baseline (1089.309 us; speedup 1.0000x reference)
//
#include <hip/hip_runtime.h>
#include <hip/hip_bf16.h>
#include <math.h>

// Problem constants (fixed by the reference)
#define NN     100000   // nodes
#define GG     2000     // graphs
#define HH     4        // heads
#define DD     64       // per-head dim
#define HID    256      // H*D
#define INF_   64       // in feats
#define EXTRA  8        // graph feats

// ---------------- GEMM: C[M,256] = A[M,K] @ B[K,256] ----------------
__global__ __launch_bounds__(256) void gemm_kernel(
    const float* __restrict__ A, const float* __restrict__ B,
    float* __restrict__ C, int M, int K)
{
    __shared__ float As[64][17];
    __shared__ float Bs[16][64];
    const int tid = threadIdx.x;
    const int tx = tid & 15, ty = tid >> 4;
    const int r0 = blockIdx.x * 64;
    const int c0 = blockIdx.y * 64;
    float acc[4][4] = {};
    for (int k0 = 0; k0 < K; k0 += 16) {
        {   // A tile: 64 rows x 16 k
            int row = tid >> 2;
            int kq  = (tid & 3) * 4;
            int gr  = r0 + row;
            float4 v = make_float4(0.f, 0.f, 0.f, 0.f);
            if (gr < M)
                v = *reinterpret_cast<const float4*>(A + (size_t)gr * K + k0 + kq);
            As[row][kq + 0] = v.x; As[row][kq + 1] = v.y;
            As[row][kq + 2] = v.z; As[row][kq + 3] = v.w;
        }
        {   // B tile: 16 k x 64 cols
            int r = tid >> 4;
            int c = (tid & 15) * 4;
            float4 v = *reinterpret_cast<const float4*>(B + (size_t)(k0 + r) * HID + c0 + c);
            *reinterpret_cast<float4*>(&Bs[r][c]) = v;
        }
        __syncthreads();
        #pragma unroll
        for (int k = 0; k < 16; ++k) {
            float b0 = Bs[k][tx * 4 + 0], b1 = Bs[k][tx * 4 + 1];
            float b2 = Bs[k][tx * 4 + 2], b3 = Bs[k][tx * 4 + 3];
            #pragma unroll
            for (int i = 0; i < 4; ++i) {
                float a = As[ty * 4 + i][k];
                acc[i][0] += a * b0; acc[i][1] += a * b1;
                acc[i][2] += a * b2; acc[i][3] += a * b3;
            }
        }
        __syncthreads();
    }
    #pragma unroll
    for (int i = 0; i < 4; ++i) {
        int gr = r0 + ty * 4 + i;
        if (gr < M) {
            float4 v = make_float4(acc[i][0], acc[i][1], acc[i][2], acc[i][3]);
            *reinterpret_cast<float4*>(C + (size_t)gr * HID + c0 + tx * 4) = v;
        }
    }
}

// ---------------- el/er: per (node, head) dot with al/ar ----------------
__global__ __launch_bounds__(256) void elr_kernel(
    const float* __restrict__ F, const float* __restrict__ al,
    const float* __restrict__ ar, float* __restrict__ el, float* __restrict__ er)
{
    int idx = blockIdx.x * blockDim.x + threadIdx.x;   // (n,h)
    if (idx >= NN * HH) return;
    int n = idx >> 2, h = idx & 3;
    const float* f  = F  + (size_t)n * HID + h * DD;
    const float* a1 = al + h * DD;
    const float* a2 = ar + h * DD;
    float s1 = 0.f, s2 = 0.f;
    #pragma unroll 4
    for (int d = 0; d < DD; d += 4) {
        float4 fv = *reinterpret_cast<const float4*>(f + d);
        float4 av = *reinterpret_cast<const float4*>(a1 + d);
        float4 bv = *reinterpret_cast<const float4*>(a2 + d);
        s1 += fv.x * av.x + fv.y * av.y + fv.z * av.z + fv.w * av.w;
        s2 += fv.x * bv.x + fv.y * bv.y + fv.z * bv.z + fv.w * bv.w;
    }
    el[idx] = s1;
    er[idx] = s2;
}

__device__ __forceinline__ float leaky02(float x) { return x > 0.f ? x : 0.2f * x; }

// ---------------- per-dst gather aggregate (edge softmax fused) ----------------
__global__ __launch_bounds__(256) void aggregate_kernel(
    const float* __restrict__ F, const float* __restrict__ el,
    const float* __restrict__ er, const int* __restrict__ rowptr,
    const int* __restrict__ colsrc, const float* __restrict__ bias,
    float* __restrict__ out)
{
    int t = blockIdx.x * 4 + (threadIdx.x >> 6);
    int lane = threadIdx.x & 63;
    if (t >= NN) return;
    int beg = rowptr[t], end = rowptr[t + 1];
    float4 ert = *reinterpret_cast<const float4*>(er + (size_t)t * 4);
    float m0 = -1e30f, m1 = -1e30f, m2 = -1e30f, m3 = -1e30f;
    for (int i = beg; i < end; ++i) {
        int s = colsrc[i];
        float4 e = *reinterpret_cast<const float4*>(el + (size_t)s * 4);
        m0 = fmaxf(m0, leaky02(e.x + ert.x));
        m1 = fmaxf(m1, leaky02(e.y + ert.y));
        m2 = fmaxf(m2, leaky02(e.z + ert.z));
        m3 = fmaxf(m3, leaky02(e.w + ert.w));
    }
    float a0 = 0.f, a1 = 0.f, a2 = 0.f, a3 = 0.f;
    float d0 = 0.f, d1 = 0.f, d2 = 0.f, d3 = 0.f;
    for (int i = beg; i < end; ++i) {
        int s = colsrc[i];
        float4 e = *reinterpret_cast<const float4*>(el + (size_t)s * 4);
        float w0 = expf(leaky02(e.x + ert.x) - m0);
        float w1 = expf(leaky02(e.y + ert.y) - m1);
        float w2 = expf(leaky02(e.z + ert.z) - m2);
        float w3 = expf(leaky02(e.w + ert.w) - m3);
        d0 += w0; d1 += w1; d2 += w2; d3 += w3;
        const float* Fs = F + (size_t)s * HID;
        a0 += w0 * Fs[lane];
        a1 += w1 * Fs[64 + lane];
        a2 += w2 * Fs[128 + lane];
        a3 += w3 * Fs[192 + lane];
    }
    float* o = out + (size_t)t * HID;
    o[lane]       = fmaxf(a0 / d0 + bias[lane], 0.f);
    o[64 + lane]  = fmaxf(a1 / d1 + bias[64 + lane], 0.f);
    o[128 + lane] = fmaxf(a2 / d2 + bias[128 + lane], 0.f);
    o[192 + lane] = fmaxf(a3 / d3 + bias[192 + lane], 0.f);
}

// ---------------- weighted-average readout: one wave per graph ----------------
__global__ __launch_bounds__(256) void readout_kernel(
    const float* __restrict__ X, const float* __restrict__ Ws,
    const float* __restrict__ bs, const int* __restrict__ gptr,
    float* __restrict__ emb)
{
    int g = blockIdx.x * 4 + (threadIdx.x >> 6);
    int lane = threadIdx.x & 63;
    if (g >= GG) return;
    int beg = gptr[g], end = gptr[g + 1];
    float w0 = Ws[lane], w1 = Ws[64 + lane], w2 = Ws[128 + lane], w3 = Ws[192 + lane];
    float b = bs[0];
    float a0 = 0.f, a1 = 0.f, a2 = 0.f, a3 = 0.f, wsum = 0.f;
    for (int n = beg; n < end; ++n) {
        const float* x = X + (size_t)n * HID;
        float x0 = x[lane], x1 = x[64 + lane], x2 = x[128 + lane], x3 = x[192 + lane];
        float p = x0 * w0 + x1 * w1 + x2 * w2 + x3 * w3;
        #pragma unroll
        for (int off = 32; off; off >>= 1) p += __shfl_xor(p, off, 64);
        float w = 1.f / (1.f + expf(-(p + b)));
        wsum += w;
        a0 += w * x0; a1 += w * x1; a2 += w * x2; a3 += w * x3;
    }
    float inv = (wsum == 0.f) ? 1.f : wsum;
    float* e = emb + (size_t)g * HID;
    e[lane] = a0 / inv; e[64 + lane] = a1 / inv;
    e[128 + lane] = a2 / inv; e[192 + lane] = a3 / inv;
}

__device__ __forceinline__ float selu_f(float x)
{
    const float scale = 1.0507009873554805f, alpha = 1.6732632423543772f;
    return scale * (x > 0.f ? x : alpha * expm1f(x));
}

// ---------------- MLP head: one block (128 thr) per graph ----------------
__global__ __launch_bounds__(128) void mlp_kernel(
    const float* __restrict__ emb, const float* __restrict__ fg,
    const float* __restrict__ Wm1, const float* __restrict__ bm1,
    const float* __restrict__ Wm2, const float* __restrict__ bm2,
    const float* __restrict__ Wm3, const float* __restrict__ bm3,
    float* __restrict__ out)
{
    int g = blockIdx.x;
    __shared__ float h[HID + EXTRA];
    __shared__ float h1[128];
    __shared__ float h2[64];
    int tid = threadIdx.x;
    h[tid] = emb[(size_t)g * HID + tid];
    h[128 + tid] = emb[(size_t)g * HID + 128 + tid];
    if (tid < EXTRA) h[HID + tid] = fg[(size_t)g * EXTRA + tid];
    __syncthreads();
    float acc = bm1[tid];
    for (int i = 0; i < HID + EXTRA; ++i) acc += h[i] * Wm1[i * 128 + tid];
    h1[tid] = selu_f(acc);
    __syncthreads();
    if (tid < 64) {
        float acc2 = bm2[tid];
        for (int i = 0; i < 128; ++i) acc2 += h1[i] * Wm2[i * 64 + tid];
        h2[tid] = selu_f(acc2);
    }
    __syncthreads();
    if (tid < 64) {
        float p = h2[tid] * Wm3[tid];
        #pragma unroll
        for (int off = 32; off; off >>= 1) p += __shfl_xor(p, off, 64);
        if (tid == 0) out[g] = p + bm3[0];
    }
}

// ---------------- CSR build helpers ----------------
__global__ void count_dst_kernel(const int* __restrict__ dst, int* __restrict__ cnt, int E)
{
    int e = blockIdx.x * 256 + threadIdx.x;
    if (e < E) atomicAdd(&cnt[dst[e]], 1);
}
__global__ void count_gid_kernel(const int* __restrict__ gid, int* __restrict__ cnt, int n)
{
    int i = blockIdx.x * 256 + threadIdx.x;
    if (i < n) atomicAdd(&cnt[gid[i]], 1);
}
__global__ void fill_csr_kernel(const int* __restrict__ src, const int* __restrict__ dst,
                                int* __restrict__ cursor, int* __restrict__ colsrc, int E)
{
    int e = blockIdx.x * 256 + threadIdx.x;
    if (e < E) {
        int p = atomicAdd(&cursor[dst[e]], 1);
        colsrc[p] = src[e];
    }
}

// exclusive scan, 1024 elems/block
__global__ __launch_bounds__(256) void scan_blocks_kernel(
    const int* __restrict__ in, int n, int* __restrict__ out, int* __restrict__ partials)
{
    __shared__ int lds[256];
    int tid = threadIdx.x;
    int base = blockIdx.x * 1024 + tid * 4;
    int v0 = (base + 0 < n) ? in[base + 0] : 0;
    int v1 = (base + 1 < n) ? in[base + 1] : 0;
    int v2 = (base + 2 < n) ? in[base + 2] : 0;
    int v3 = (base + 3 < n) ? in[base + 3] : 0;
    int s = v0 + v1 + v2 + v3;
    lds[tid] = s;
    __syncthreads();
    for (int off = 1; off < 256; off <<= 1) {
        int t = (tid >= off) ? lds[tid - off] : 0;
        __syncthreads();
        lds[tid] += t;
        __syncthreads();
    }
    int excl = lds[tid] - s;
    if (base + 0 < n) out[base + 0] = excl;
    if (base + 1 < n) out[base + 1] = excl + v0;
    if (base + 2 < n) out[base + 2] = excl + v0 + v1;
    if (base + 3 < n) out[base + 3] = excl + v0 + v1 + v2;
    if (tid == 255) partials[blockIdx.x] = lds[255];
}

__global__ __launch_bounds__(256) void scan_partials_kernel(int* partials, int nb)
{
    __shared__ int lds[256];
    int tid = threadIdx.x;
    int v = (tid < nb) ? partials[tid] : 0;
    lds[tid] = v;
    __syncthreads();
    for (int off = 1; off < 256; off <<= 1) {
        int t = (tid >= off) ? lds[tid - off] : 0;
        __syncthreads();
        lds[tid] += t;
        __syncthreads();
    }
    int excl = lds[tid] - v;
    if (tid < nb) partials[tid] = excl;
}

__global__ void add_offsets_kernel(int* __restrict__ out, const int* __restrict__ partials, int n)
{
    int i = blockIdx.x * 256 + threadIdx.x;
    if (i < n) out[i] += partials[i >> 10];
}

// ---------------- launch ----------------
extern "C" void kernel_launch(void* const* d_in, const int* in_sizes, int n_in,
                              void* d_out, int out_size, void* d_ws, size_t ws_size,
                              hipStream_t stream)
{
    const float* feats_node  = (const float*)d_in[0];
    const float* feats_graph = (const float*)d_in[1];
    const float* W1  = (const float*)d_in[2];
    const float* al1 = (const float*)d_in[3];
    const float* ar1 = (const float*)d_in[4];
    const float* b1  = (const float*)d_in[5];
    const float* W2  = (const float*)d_in[6];
    const float* al2 = (const float*)d_in[7];
    const float* ar2 = (const float*)d_in[8];
    const float* b2  = (const float*)d_in[9];
    const float* Ws  = (const float*)d_in[10];
    const float* bs  = (const float*)d_in[11];
    const float* Wm1 = (const float*)d_in[12];
    const float* bm1 = (const float*)d_in[13];
    const float* Wm2 = (const float*)d_in[14];
    const float* bm2 = (const float*)d_in[15];
    const float* Wm3 = (const float*)d_in[16];
    const float* bm3 = (const float*)d_in[17];
    const int* src = (const int*)d_in[18];
    const int* dst = (const int*)d_in[19];
    const int* gid = (const int*)d_in[20];
    float* out = (float*)d_out;
    const int E = in_sizes[18];   // 900000

    // workspace carve-up (256B aligned)
    char* p = (char*)d_ws;
    auto alloc = [&](size_t bytes) {
        char* r = p;
        p += (bytes + 255) & ~(size_t)255;
        return r;
    };
    float* F      = (float*)alloc((size_t)NN * HID * 4);
    float* X      = (float*)alloc((size_t)NN * HID * 4);
    float* el     = (float*)alloc((size_t)NN * HH * 4);
    float* er     = (float*)alloc((size_t)NN * HH * 4);
    int*   cnt    = (int*)alloc((size_t)(NN + 1) * 4);
    int*   rowptr = (int*)alloc((size_t)(NN + 1) * 4);
    int*   cursor = (int*)alloc((size_t)(NN + 1) * 4);
    int*   colsrc = (int*)alloc((size_t)E * 4);
    int*   gcnt   = (int*)alloc((size_t)(GG + 1) * 4);
    int*   gptr   = (int*)alloc((size_t)(GG + 1) * 4);
    int*   parts  = (int*)alloc(1024 * 4);
    float* emb    = (float*)alloc((size_t)GG * HID * 4);

    // ---- CSR over dst ----
    hipMemsetAsync(cnt, 0, (size_t)(NN + 1) * 4, stream);
    count_dst_kernel<<<(E + 255) / 256, 256, 0, stream>>>(dst, cnt, E);
    {
        int n = NN + 1, nb = (n + 1023) / 1024;
        scan_blocks_kernel<<<nb, 256, 0, stream>>>(cnt, n, rowptr, parts);
        scan_partials_kernel<<<1, 256, 0, stream>>>(parts, nb);
        add_offsets_kernel<<<(n + 255) / 256, 256, 0, stream>>>(rowptr, parts, n);
    }
    hipMemcpyAsync(cursor, rowptr, (size_t)(NN + 1) * 4, hipMemcpyDeviceToDevice, stream);
    fill_csr_kernel<<<(E + 255) / 256, 256, 0, stream>>>(src, dst, cursor, colsrc, E);

    // ---- graph ranges (node_gid is sorted) ----
    hipMemsetAsync(gcnt, 0, (size_t)(GG + 1) * 4, stream);
    count_gid_kernel<<<(NN + 255) / 256, 256, 0, stream>>>(gid, gcnt, NN);
    {
        int n = GG + 1, nb = (n + 1023) / 1024;
        scan_blocks_kernel<<<nb, 256, 0, stream>>>(gcnt, n, gptr, parts);
        scan_partials_kernel<<<1, 256, 0, stream>>>(parts, nb);
        add_offsets_kernel<<<(n + 255) / 256, 256, 0, stream>>>(gptr, parts, n);
    }

    dim3 ggrid((NN + 63) / 64, HID / 64);

    // ---- GAT layer 1 ----
    gemm_kernel<<<ggrid, 256, 0, stream>>>(feats_node, W1, F, NN, INF_);
    elr_kernel<<<(NN * HH + 255) / 256, 256, 0, stream>>>(F, al1, ar1, el, er);
    aggregate_kernel<<<(NN + 3) / 4, 256, 0, stream>>>(F, el, er, rowptr, colsrc, b1, X);

    // ---- GAT layer 2 ----
    gemm_kernel<<<ggrid, 256, 0, stream>>>(X, W2, F, NN, HID);
    elr_kernel<<<(NN * HH + 255) / 256, 256, 0, stream>>>(F, al2, ar2, el, er);
    aggregate_kernel<<<(NN + 3) / 4, 256, 0, stream>>>(F, el, er, rowptr, colsrc, b2, X);

    // ---- readout + MLP ----
    readout_kernel<<<(GG + 3) / 4, 256, 0, stream>>>(X, Ws, bs, gptr, emb);
    mlp_kernel<<<GG, 128, 0, stream>>>(emb, feats_graph, Wm1, bm1, Wm2, bm2, Wm3, bm3, out);
}

// Round 2
// 961.936 us; speedup vs baseline: 1.1324x; 1.1324x over previous
//
#include <hip/hip_runtime.h>
#include <hip/hip_bf16.h>
#include <math.h>

// Problem constants (fixed by the reference)
#define NN     100000   // nodes
#define GG     2000     // graphs
#define HH     4        // heads
#define DD     64       // per-head dim
#define HID    256      // H*D
#define INF_   64       // in feats
#define EXTRA  8        // graph feats

// ---------------- GEMM: C[M,256] = A[M,K] @ B[K,256] ----------------
__global__ __launch_bounds__(256) void gemm_kernel(
    const float* __restrict__ A, const float* __restrict__ B,
    float* __restrict__ C, int M, int K)
{
    __shared__ float As[64][17];
    __shared__ float Bs[16][64];
    const int tid = threadIdx.x;
    const int tx = tid & 15, ty = tid >> 4;
    const int r0 = blockIdx.x * 64;
    const int c0 = blockIdx.y * 64;
    float acc[4][4] = {};
    for (int k0 = 0; k0 < K; k0 += 16) {
        {   // A tile: 64 rows x 16 k
            int row = tid >> 2;
            int kq  = (tid & 3) * 4;
            int gr  = r0 + row;
            float4 v = make_float4(0.f, 0.f, 0.f, 0.f);
            if (gr < M)
                v = *reinterpret_cast<const float4*>(A + (size_t)gr * K + k0 + kq);
            As[row][kq + 0] = v.x; As[row][kq + 1] = v.y;
            As[row][kq + 2] = v.z; As[row][kq + 3] = v.w;
        }
        {   // B tile: 16 k x 64 cols
            int r = tid >> 4;
            int c = (tid & 15) * 4;
            float4 v = *reinterpret_cast<const float4*>(B + (size_t)(k0 + r) * HID + c0 + c);
            *reinterpret_cast<float4*>(&Bs[r][c]) = v;
        }
        __syncthreads();
        #pragma unroll
        for (int k = 0; k < 16; ++k) {
            float b0 = Bs[k][tx * 4 + 0], b1 = Bs[k][tx * 4 + 1];
            float b2 = Bs[k][tx * 4 + 2], b3 = Bs[k][tx * 4 + 3];
            #pragma unroll
            for (int i = 0; i < 4; ++i) {
                float a = As[ty * 4 + i][k];
                acc[i][0] += a * b0; acc[i][1] += a * b1;
                acc[i][2] += a * b2; acc[i][3] += a * b3;
            }
        }
        __syncthreads();
    }
    #pragma unroll
    for (int i = 0; i < 4; ++i) {
        int gr = r0 + ty * 4 + i;
        if (gr < M) {
            float4 v = make_float4(acc[i][0], acc[i][1], acc[i][2], acc[i][3]);
            *reinterpret_cast<float4*>(C + (size_t)gr * HID + c0 + tx * 4) = v;
        }
    }
}

// ---------------- el/er: per (node, head) dot with al/ar ----------------
__global__ __launch_bounds__(256) void elr_kernel(
    const float* __restrict__ F, const float* __restrict__ al,
    const float* __restrict__ ar, float* __restrict__ el, float* __restrict__ er)
{
    int idx = blockIdx.x * blockDim.x + threadIdx.x;   // (n,h)
    if (idx >= NN * HH) return;
    int n = idx >> 2, h = idx & 3;
    const float* f  = F  + (size_t)n * HID + h * DD;
    const float* a1 = al + h * DD;
    const float* a2 = ar + h * DD;
    float s1 = 0.f, s2 = 0.f;
    #pragma unroll 4
    for (int d = 0; d < DD; d += 4) {
        float4 fv = *reinterpret_cast<const float4*>(f + d);
        float4 av = *reinterpret_cast<const float4*>(a1 + d);
        float4 bv = *reinterpret_cast<const float4*>(a2 + d);
        s1 += fv.x * av.x + fv.y * av.y + fv.z * av.z + fv.w * av.w;
        s2 += fv.x * bv.x + fv.y * bv.y + fv.z * bv.z + fv.w * bv.w;
    }
    el[idx] = s1;
    er[idx] = s2;
}

__device__ __forceinline__ float leaky02(float x) { return x > 0.f ? x : 0.2f * x; }

// ---------------- edge softmax: one thread per (dst-node, head) ----------------
// Writes unnormalized w[e][h] and invden[t][h]; removes all transcendental
// work from the wave-redundant aggregate path.
__global__ __launch_bounds__(256) void edge_softmax_kernel(
    const float* __restrict__ el, const float* __restrict__ er,
    const int* __restrict__ rowptr, const int* __restrict__ colsrc,
    float* __restrict__ w, float* __restrict__ invden)
{
    int idx = blockIdx.x * 256 + threadIdx.x;   // (t,h)
    if (idx >= NN * HH) return;
    int t = idx >> 2, h = idx & 3;
    int beg = rowptr[t], end = rowptr[t + 1];
    float ert = er[idx];
    float m = -1e30f;
    for (int i = beg; i < end; ++i) {
        int s = colsrc[i];
        m = fmaxf(m, leaky02(el[s * 4 + h] + ert));
    }
    float den = 0.f;
    for (int i = beg; i < end; ++i) {
        int s = colsrc[i];
        float v = expf(leaky02(el[s * 4 + h] + ert) - m);
        w[(size_t)i * 4 + h] = v;
        den += v;
    }
    invden[idx] = 1.f / den;   // deg >= 1 (self-loops), den > 0
}

// ---------------- per-dst gather aggregate (pure weighted gather) ----------------
__global__ __launch_bounds__(256) void aggregate_kernel(
    const float* __restrict__ F, const float* __restrict__ w,
    const float* __restrict__ invden, const int* __restrict__ rowptr,
    const int* __restrict__ colsrc, const float* __restrict__ bias,
    float* __restrict__ out)
{
    int t = blockIdx.x * 4 + (threadIdx.x >> 6);
    int lane = threadIdx.x & 63;
    if (t >= NN) return;
    int beg = rowptr[t], end = rowptr[t + 1];
    float a0 = 0.f, a1 = 0.f, a2 = 0.f, a3 = 0.f;
    for (int i = beg; i < end; ++i) {
        int s = colsrc[i];
        float4 wv = *reinterpret_cast<const float4*>(w + (size_t)i * 4);
        const float* Fs = F + (size_t)s * HID;
        a0 += wv.x * Fs[lane];
        a1 += wv.y * Fs[64 + lane];
        a2 += wv.z * Fs[128 + lane];
        a3 += wv.w * Fs[192 + lane];
    }
    float4 inv = *reinterpret_cast<const float4*>(invden + (size_t)t * 4);
    float* o = out + (size_t)t * HID;
    o[lane]       = fmaxf(a0 * inv.x + bias[lane], 0.f);
    o[64 + lane]  = fmaxf(a1 * inv.y + bias[64 + lane], 0.f);
    o[128 + lane] = fmaxf(a2 * inv.z + bias[128 + lane], 0.f);
    o[192 + lane] = fmaxf(a3 * inv.w + bias[192 + lane], 0.f);
}

// ---------------- weighted-average readout: one wave per graph ----------------
__global__ __launch_bounds__(256) void readout_kernel(
    const float* __restrict__ X, const float* __restrict__ Ws,
    const float* __restrict__ bs, const int* __restrict__ gptr,
    float* __restrict__ emb)
{
    int g = blockIdx.x * 4 + (threadIdx.x >> 6);
    int lane = threadIdx.x & 63;
    if (g >= GG) return;
    int beg = gptr[g], end = gptr[g + 1];
    float w0 = Ws[lane], w1 = Ws[64 + lane], w2 = Ws[128 + lane], w3 = Ws[192 + lane];
    float b = bs[0];
    float a0 = 0.f, a1 = 0.f, a2 = 0.f, a3 = 0.f, wsum = 0.f;
    for (int n = beg; n < end; ++n) {
        const float* x = X + (size_t)n * HID;
        float x0 = x[lane], x1 = x[64 + lane], x2 = x[128 + lane], x3 = x[192 + lane];
        float p = x0 * w0 + x1 * w1 + x2 * w2 + x3 * w3;
        #pragma unroll
        for (int off = 32; off; off >>= 1) p += __shfl_xor(p, off, 64);
        float w = 1.f / (1.f + expf(-(p + b)));
        wsum += w;
        a0 += w * x0; a1 += w * x1; a2 += w * x2; a3 += w * x3;
    }
    float inv = (wsum == 0.f) ? 1.f : wsum;
    float* e = emb + (size_t)g * HID;
    e[lane] = a0 / inv; e[64 + lane] = a1 / inv;
    e[128 + lane] = a2 / inv; e[192 + lane] = a3 / inv;
}

__device__ __forceinline__ float selu_f(float x)
{
    const float scale = 1.0507009873554805f, alpha = 1.6732632423543772f;
    return scale * (x > 0.f ? x : alpha * expm1f(x));
}

// ---------------- MLP head: one block (128 thr) per graph ----------------
__global__ __launch_bounds__(128) void mlp_kernel(
    const float* __restrict__ emb, const float* __restrict__ fg,
    const float* __restrict__ Wm1, const float* __restrict__ bm1,
    const float* __restrict__ Wm2, const float* __restrict__ bm2,
    const float* __restrict__ Wm3, const float* __restrict__ bm3,
    float* __restrict__ out)
{
    int g = blockIdx.x;
    __shared__ float h[HID + EXTRA];
    __shared__ float h1[128];
    __shared__ float h2[64];
    int tid = threadIdx.x;
    h[tid] = emb[(size_t)g * HID + tid];
    h[128 + tid] = emb[(size_t)g * HID + 128 + tid];
    if (tid < EXTRA) h[HID + tid] = fg[(size_t)g * EXTRA + tid];
    __syncthreads();
    float acc = bm1[tid];
    for (int i = 0; i < HID + EXTRA; ++i) acc += h[i] * Wm1[i * 128 + tid];
    h1[tid] = selu_f(acc);
    __syncthreads();
    if (tid < 64) {
        float acc2 = bm2[tid];
        for (int i = 0; i < 128; ++i) acc2 += h1[i] * Wm2[i * 64 + tid];
        h2[tid] = selu_f(acc2);
    }
    __syncthreads();
    if (tid < 64) {
        float p = h2[tid] * Wm3[tid];
        #pragma unroll
        for (int off = 32; off; off >>= 1) p += __shfl_xor(p, off, 64);
        if (tid == 0) out[g] = p + bm3[0];
    }
}

// ---------------- CSR build helpers ----------------
__global__ void count_dst_kernel(const int* __restrict__ dst, int* __restrict__ cnt, int E)
{
    int e = blockIdx.x * 256 + threadIdx.x;
    if (e < E) atomicAdd(&cnt[dst[e]], 1);
}
__global__ void count_gid_kernel(const int* __restrict__ gid, int* __restrict__ cnt, int n)
{
    int i = blockIdx.x * 256 + threadIdx.x;
    if (i < n) atomicAdd(&cnt[gid[i]], 1);
}
__global__ void fill_csr_kernel(const int* __restrict__ src, const int* __restrict__ dst,
                                int* __restrict__ cursor, int* __restrict__ colsrc, int E)
{
    int e = blockIdx.x * 256 + threadIdx.x;
    if (e < E) {
        int p = atomicAdd(&cursor[dst[e]], 1);
        colsrc[p] = src[e];
    }
}

// exclusive scan, 1024 elems/block
__global__ __launch_bounds__(256) void scan_blocks_kernel(
    const int* __restrict__ in, int n, int* __restrict__ out, int* __restrict__ partials)
{
    __shared__ int lds[256];
    int tid = threadIdx.x;
    int base = blockIdx.x * 1024 + tid * 4;
    int v0 = (base + 0 < n) ? in[base + 0] : 0;
    int v1 = (base + 1 < n) ? in[base + 1] : 0;
    int v2 = (base + 2 < n) ? in[base + 2] : 0;
    int v3 = (base + 3 < n) ? in[base + 3] : 0;
    int s = v0 + v1 + v2 + v3;
    lds[tid] = s;
    __syncthreads();
    for (int off = 1; off < 256; off <<= 1) {
        int t = (tid >= off) ? lds[tid - off] : 0;
        __syncthreads();
        lds[tid] += t;
        __syncthreads();
    }
    int excl = lds[tid] - s;
    if (base + 0 < n) out[base + 0] = excl;
    if (base + 1 < n) out[base + 1] = excl + v0;
    if (base + 2 < n) out[base + 2] = excl + v0 + v1;
    if (base + 3 < n) out[base + 3] = excl + v0 + v1 + v2;
    if (tid == 255) partials[blockIdx.x] = lds[255];
}

__global__ __launch_bounds__(256) void scan_partials_kernel(int* partials, int nb)
{
    __shared__ int lds[256];
    int tid = threadIdx.x;
    int v = (tid < nb) ? partials[tid] : 0;
    lds[tid] = v;
    __syncthreads();
    for (int off = 1; off < 256; off <<= 1) {
        int t = (tid >= off) ? lds[tid - off] : 0;
        __syncthreads();
        lds[tid] += t;
        __syncthreads();
    }
    int excl = lds[tid] - v;
    if (tid < nb) partials[tid] = excl;
}

__global__ void add_offsets_kernel(int* __restrict__ out, const int* __restrict__ partials, int n)
{
    int i = blockIdx.x * 256 + threadIdx.x;
    if (i < n) out[i] += partials[i >> 10];
}

// ---------------- launch ----------------
extern "C" void kernel_launch(void* const* d_in, const int* in_sizes, int n_in,
                              void* d_out, int out_size, void* d_ws, size_t ws_size,
                              hipStream_t stream)
{
    const float* feats_node  = (const float*)d_in[0];
    const float* feats_graph = (const float*)d_in[1];
    const float* W1  = (const float*)d_in[2];
    const float* al1 = (const float*)d_in[3];
    const float* ar1 = (const float*)d_in[4];
    const float* b1  = (const float*)d_in[5];
    const float* W2  = (const float*)d_in[6];
    const float* al2 = (const float*)d_in[7];
    const float* ar2 = (const float*)d_in[8];
    const float* b2  = (const float*)d_in[9];
    const float* Ws  = (const float*)d_in[10];
    const float* bs  = (const float*)d_in[11];
    const float* Wm1 = (const float*)d_in[12];
    const float* bm1 = (const float*)d_in[13];
    const float* Wm2 = (const float*)d_in[14];
    const float* bm2 = (const float*)d_in[15];
    const float* Wm3 = (const float*)d_in[16];
    const float* bm3 = (const float*)d_in[17];
    const int* src = (const int*)d_in[18];
    const int* dst = (const int*)d_in[19];
    const int* gid = (const int*)d_in[20];
    float* out = (float*)d_out;
    const int E = in_sizes[18];   // 900000

    // workspace carve-up (256B aligned)
    char* p = (char*)d_ws;
    auto alloc = [&](size_t bytes) {
        char* r = p;
        p += (bytes + 255) & ~(size_t)255;
        return r;
    };
    float* F      = (float*)alloc((size_t)NN * HID * 4);
    float* X      = (float*)alloc((size_t)NN * HID * 4);
    float* el     = (float*)alloc((size_t)NN * HH * 4);
    float* er     = (float*)alloc((size_t)NN * HH * 4);
    float* wbuf   = (float*)alloc((size_t)E * HH * 4);
    float* invden = (float*)alloc((size_t)NN * HH * 4);
    int*   cnt    = (int*)alloc((size_t)(NN + 1) * 4);
    int*   rowptr = (int*)alloc((size_t)(NN + 1) * 4);
    int*   cursor = (int*)alloc((size_t)(NN + 1) * 4);
    int*   colsrc = (int*)alloc((size_t)E * 4);
    int*   gcnt   = (int*)alloc((size_t)(GG + 1) * 4);
    int*   gptr   = (int*)alloc((size_t)(GG + 1) * 4);
    int*   parts  = (int*)alloc(1024 * 4);
    float* emb    = (float*)alloc((size_t)GG * HID * 4);

    // ---- CSR over dst ----
    hipMemsetAsync(cnt, 0, (size_t)(NN + 1) * 4, stream);
    count_dst_kernel<<<(E + 255) / 256, 256, 0, stream>>>(dst, cnt, E);
    {
        int n = NN + 1, nb = (n + 1023) / 1024;
        scan_blocks_kernel<<<nb, 256, 0, stream>>>(cnt, n, rowptr, parts);
        scan_partials_kernel<<<1, 256, 0, stream>>>(parts, nb);
        add_offsets_kernel<<<(n + 255) / 256, 256, 0, stream>>>(rowptr, parts, n);
    }
    hipMemcpyAsync(cursor, rowptr, (size_t)(NN + 1) * 4, hipMemcpyDeviceToDevice, stream);
    fill_csr_kernel<<<(E + 255) / 256, 256, 0, stream>>>(src, dst, cursor, colsrc, E);

    // ---- graph ranges (node_gid is sorted) ----
    hipMemsetAsync(gcnt, 0, (size_t)(GG + 1) * 4, stream);
    count_gid_kernel<<<(NN + 255) / 256, 256, 0, stream>>>(gid, gcnt, NN);
    {
        int n = GG + 1, nb = (n + 1023) / 1024;
        scan_blocks_kernel<<<nb, 256, 0, stream>>>(gcnt, n, gptr, parts);
        scan_partials_kernel<<<1, 256, 0, stream>>>(parts, nb);
        add_offsets_kernel<<<(n + 255) / 256, 256, 0, stream>>>(gptr, parts, n);
    }

    dim3 ggrid((NN + 63) / 64, HID / 64);
    const int nh_blocks = (NN * HH + 255) / 256;

    // ---- GAT layer 1 ----
    gemm_kernel<<<ggrid, 256, 0, stream>>>(feats_node, W1, F, NN, INF_);
    elr_kernel<<<nh_blocks, 256, 0, stream>>>(F, al1, ar1, el, er);
    edge_softmax_kernel<<<nh_blocks, 256, 0, stream>>>(el, er, rowptr, colsrc, wbuf, invden);
    aggregate_kernel<<<(NN + 3) / 4, 256, 0, stream>>>(F, wbuf, invden, rowptr, colsrc, b1, X);

    // ---- GAT layer 2 ----
    gemm_kernel<<<ggrid, 256, 0, stream>>>(X, W2, F, NN, HID);
    elr_kernel<<<nh_blocks, 256, 0, stream>>>(F, al2, ar2, el, er);
    edge_softmax_kernel<<<nh_blocks, 256, 0, stream>>>(el, er, rowptr, colsrc, wbuf, invden);
    aggregate_kernel<<<(NN + 3) / 4, 256, 0, stream>>>(F, wbuf, invden, rowptr, colsrc, b2, X);

    // ---- readout + MLP ----
    readout_kernel<<<(GG + 3) / 4, 256, 0, stream>>>(X, Ws, bs, gptr, emb);
    mlp_kernel<<<GG, 128, 0, stream>>>(emb, feats_graph, Wm1, bm1, Wm2, bm2, Wm3, bm3, out);
}

// Round 6
// 803.926 us; speedup vs baseline: 1.3550x; 1.1965x over previous
//
#include <hip/hip_runtime.h>
#include <hip/hip_bf16.h>
#include <math.h>

// Problem constants (fixed by the reference)
#define NN     100000   // nodes
#define GG     2000     // graphs
#define HH     4        // heads
#define DD     64       // per-head dim
#define HID    256      // H*D
#define INF_   64       // in feats
#define EXTRA  8        // graph feats

typedef unsigned short u16;
typedef __attribute__((ext_vector_type(8))) short bf16x8;
typedef __attribute__((ext_vector_type(4))) float f32x4;

__device__ __forceinline__ u16 f2bf(float f) {
    unsigned u = __float_as_uint(f);
    return (u16)((u + 0x7fffu + ((u >> 16) & 1u)) >> 16);
}
__device__ __forceinline__ float bf2f(u16 v) {
    return __uint_as_float(((unsigned)v) << 16);
}

// ---------------- W [K,256] -> transposed hi/lo bf16 [256,K] ----------------
__global__ __launch_bounds__(256) void wsplit_kernel(
    const float* __restrict__ W, u16* __restrict__ hi, u16* __restrict__ lo,
    int K, int lgK)
{
    int idx = blockIdx.x * 256 + threadIdx.x;   // n*K + k
    if (idx >= 256 * K) return;
    int n = idx >> lgK, k = idx & (K - 1);
    float w = W[k * HID + n];
    u16 h = f2bf(w);
    hi[idx] = h;
    lo[idx] = f2bf(w - bf2f(h));
}

// ---------------- MFMA GEMM, split-split numerics ----------------
// C[M,256](f32) = A_f32[M,K] @ B ; A split hi+lo in-register during staging,
// B pre-split hi+lo (wsplit). Per fragment: Ah*Bh + Al*Bh + Ah*Bl (the
// dropped Al*Bl term is ~2^-18 relative) -> near-f32 product accuracy.
// This matters: single-bf16 activations perturb attention logits by ~0.13
// which becomes ~25% attention-weight error (rounds 4/5, absmax 130).
// 128x128 tile, 4 waves, each wave 64x64 = 4x4 tiles of 16x16x32.
__global__ __launch_bounds__(256) void mfma_gemm_kernel(
    const float* __restrict__ A, const u16* __restrict__ BThi,
    const u16* __restrict__ BTlo, float* __restrict__ C, int M, int K)
{
    __shared__ __align__(16) u16 Ah[128 * 40];
    __shared__ __align__(16) u16 Al[128 * 40];
    __shared__ __align__(16) u16 Bh[128 * 40];
    __shared__ __align__(16) u16 Bl[128 * 40];
    const int tid  = threadIdx.x;
    const int wave = tid >> 6, lane = tid & 63;
    const int quad = lane >> 4, l15 = lane & 15;
    const int wy = wave >> 1, wx = wave & 1;
    const int r0 = blockIdx.x * 128, c0 = blockIdx.y * 128;
    const int sr = tid >> 2, sseg = tid & 3;

    f32x4 acc[4][4];
    #pragma unroll
    for (int i = 0; i < 4; ++i)
        #pragma unroll
        for (int j = 0; j < 4; ++j)
            acc[i][j] = (f32x4){0.f, 0.f, 0.f, 0.f};

    for (int k0 = 0; k0 < K; k0 += 32) {
        #pragma unroll
        for (int half = 0; half < 2; ++half) {
            int r = sr + half * 64;
            int gr = min(r0 + r, M - 1);
            const float* ap = A + (size_t)gr * K + k0 + sseg * 8;
            float4 va0 = *reinterpret_cast<const float4*>(ap);
            float4 va1 = *reinterpret_cast<const float4*>(ap + 4);
            float av[8] = {va0.x, va0.y, va0.z, va0.w, va1.x, va1.y, va1.z, va1.w};
            bf16x8 vh, vl;
            #pragma unroll
            for (int m = 0; m < 8; ++m) {
                u16 h = f2bf(av[m]);
                vh[m] = (short)h;
                vl[m] = (short)f2bf(av[m] - bf2f(h));
            }
            *reinterpret_cast<bf16x8*>(&Ah[r * 40 + sseg * 8]) = vh;
            *reinterpret_cast<bf16x8*>(&Al[r * 40 + sseg * 8]) = vl;
            int gc = c0 + r;   // < 256 always
            *reinterpret_cast<bf16x8*>(&Bh[r * 40 + sseg * 8]) =
                *reinterpret_cast<const bf16x8*>(BThi + (size_t)gc * K + k0 + sseg * 8);
            *reinterpret_cast<bf16x8*>(&Bl[r * 40 + sseg * 8]) =
                *reinterpret_cast<const bf16x8*>(BTlo + (size_t)gc * K + k0 + sseg * 8);
        }
        __syncthreads();
        bf16x8 afh[4], afl[4], bfh[4], bfl[4];
        #pragma unroll
        for (int i = 0; i < 4; ++i) {
            int row = (wy * 64 + i * 16 + l15) * 40 + quad * 8;
            afh[i] = *reinterpret_cast<const bf16x8*>(&Ah[row]);
            afl[i] = *reinterpret_cast<const bf16x8*>(&Al[row]);
        }
        #pragma unroll
        for (int j = 0; j < 4; ++j) {
            int row = (wx * 64 + j * 16 + l15) * 40 + quad * 8;
            bfh[j] = *reinterpret_cast<const bf16x8*>(&Bh[row]);
            bfl[j] = *reinterpret_cast<const bf16x8*>(&Bl[row]);
        }
        #pragma unroll
        for (int i = 0; i < 4; ++i)
            #pragma unroll
            for (int j = 0; j < 4; ++j) {
                acc[i][j] = __builtin_amdgcn_mfma_f32_16x16x32_bf16(afh[i], bfh[j], acc[i][j], 0, 0, 0);
                acc[i][j] = __builtin_amdgcn_mfma_f32_16x16x32_bf16(afl[i], bfh[j], acc[i][j], 0, 0, 0);
                acc[i][j] = __builtin_amdgcn_mfma_f32_16x16x32_bf16(afh[i], bfl[j], acc[i][j], 0, 0, 0);
            }
        __syncthreads();
    }
    // C/D layout: col = l15, row = quad*4 + rr
    #pragma unroll
    for (int i = 0; i < 4; ++i)
        #pragma unroll
        for (int rr = 0; rr < 4; ++rr) {
            int grow = r0 + wy * 64 + i * 16 + quad * 4 + rr;
            if (grow < M) {
                float* crow = C + (size_t)grow * HID + c0 + wx * 64 + l15;
                #pragma unroll
                for (int j = 0; j < 4; ++j) crow[j * 16] = acc[i][j][rr];
            }
        }
}

// ---------------- el/er: per (node, head) dot with al/ar ----------------
__global__ __launch_bounds__(256) void elr_kernel(
    const float* __restrict__ F, const float* __restrict__ al,
    const float* __restrict__ ar, float* __restrict__ el, float* __restrict__ er)
{
    int idx = blockIdx.x * blockDim.x + threadIdx.x;   // (n,h)
    if (idx >= NN * HH) return;
    int n = idx >> 2, h = idx & 3;
    const float* f  = F  + (size_t)n * HID + h * DD;
    const float* a1 = al + h * DD;
    const float* a2 = ar + h * DD;
    float s1 = 0.f, s2 = 0.f;
    #pragma unroll 4
    for (int d = 0; d < DD; d += 4) {
        float4 fv = *reinterpret_cast<const float4*>(f + d);
        float4 av = *reinterpret_cast<const float4*>(a1 + d);
        float4 bv = *reinterpret_cast<const float4*>(a2 + d);
        s1 += fv.x * av.x + fv.y * av.y + fv.z * av.z + fv.w * av.w;
        s2 += fv.x * bv.x + fv.y * bv.y + fv.z * bv.z + fv.w * bv.w;
    }
    el[idx] = s1;
    er[idx] = s2;
}

__device__ __forceinline__ float leaky02(float x) { return x > 0.f ? x : 0.2f * x; }

// ---------------- edge softmax: one thread per (dst-node, head) ----------------
__global__ __launch_bounds__(256) void edge_softmax_kernel(
    const float* __restrict__ el, const float* __restrict__ er,
    const int* __restrict__ rowptr, const int* __restrict__ colsrc,
    float* __restrict__ w, float* __restrict__ invden)
{
    int idx = blockIdx.x * 256 + threadIdx.x;   // (t,h)
    if (idx >= NN * HH) return;
    int t = idx >> 2, h = idx & 3;
    int beg = rowptr[t], end = rowptr[t + 1];
    float ert = er[idx];
    float m = -1e30f;
    for (int i = beg; i < end; ++i) {
        int s = colsrc[i];
        m = fmaxf(m, leaky02(el[s * 4 + h] + ert));
    }
    float den = 0.f;
    for (int i = beg; i < end; ++i) {
        int s = colsrc[i];
        float v = expf(leaky02(el[s * 4 + h] + ert) - m);
        w[(size_t)i * 4 + h] = v;
        den += v;
    }
    invden[idx] = 1.f / den;   // deg >= 1 (self-loops), den > 0
}

// ---------------- per-dst gather aggregate (pure weighted gather, f32) --------
__global__ __launch_bounds__(256) void aggregate_kernel(
    const float* __restrict__ F, const float* __restrict__ w,
    const float* __restrict__ invden, const int* __restrict__ rowptr,
    const int* __restrict__ colsrc, const float* __restrict__ bias,
    float* __restrict__ out)
{
    int t = blockIdx.x * 4 + (threadIdx.x >> 6);
    int lane = threadIdx.x & 63;
    if (t >= NN) return;
    int beg = rowptr[t], end = rowptr[t + 1];
    float a0 = 0.f, a1 = 0.f, a2 = 0.f, a3 = 0.f;
    for (int i = beg; i < end; ++i) {
        int s = colsrc[i];
        float4 wv = *reinterpret_cast<const float4*>(w + (size_t)i * 4);
        const float* Fs = F + (size_t)s * HID;
        a0 += wv.x * Fs[lane];
        a1 += wv.y * Fs[64 + lane];
        a2 += wv.z * Fs[128 + lane];
        a3 += wv.w * Fs[192 + lane];
    }
    float4 inv = *reinterpret_cast<const float4*>(invden + (size_t)t * 4);
    float* o = out + (size_t)t * HID;
    o[lane]       = fmaxf(a0 * inv.x + bias[lane], 0.f);
    o[64 + lane]  = fmaxf(a1 * inv.y + bias[64 + lane], 0.f);
    o[128 + lane] = fmaxf(a2 * inv.z + bias[128 + lane], 0.f);
    o[192 + lane] = fmaxf(a3 * inv.w + bias[192 + lane], 0.f);
}

// ---------------- weighted-average readout: one wave per graph ----------------
__global__ __launch_bounds__(256) void readout_kernel(
    const float* __restrict__ X, const float* __restrict__ Ws,
    const float* __restrict__ bs, const int* __restrict__ gptr,
    float* __restrict__ emb)
{
    int g = blockIdx.x * 4 + (threadIdx.x >> 6);
    int lane = threadIdx.x & 63;
    if (g >= GG) return;
    int beg = gptr[g], end = gptr[g + 1];
    float w0 = Ws[lane], w1 = Ws[64 + lane], w2 = Ws[128 + lane], w3 = Ws[192 + lane];
    float b = bs[0];
    float a0 = 0.f, a1 = 0.f, a2 = 0.f, a3 = 0.f, wsum = 0.f;
    for (int n = beg; n < end; ++n) {
        const float* x = X + (size_t)n * HID;
        float x0 = x[lane], x1 = x[64 + lane], x2 = x[128 + lane], x3 = x[192 + lane];
        float p = x0 * w0 + x1 * w1 + x2 * w2 + x3 * w3;
        #pragma unroll
        for (int off = 32; off; off >>= 1) p += __shfl_xor(p, off, 64);
        float w = 1.f / (1.f + expf(-(p + b)));
        wsum += w;
        a0 += w * x0; a1 += w * x1; a2 += w * x2; a3 += w * x3;
    }
    float inv = (wsum == 0.f) ? 1.f : wsum;
    float* e = emb + (size_t)g * HID;
    e[lane] = a0 / inv; e[64 + lane] = a1 / inv;
    e[128 + lane] = a2 / inv; e[192 + lane] = a3 / inv;
}

__device__ __forceinline__ float selu_f(float x)
{
    const float scale = 1.0507009873554805f, alpha = 1.6732632423543772f;
    return scale * (x > 0.f ? x : alpha * expm1f(x));
}

// ---------------- MLP head: one block (128 thr) per graph ----------------
__global__ __launch_bounds__(128) void mlp_kernel(
    const float* __restrict__ emb, const float* __restrict__ fg,
    const float* __restrict__ Wm1, const float* __restrict__ bm1,
    const float* __restrict__ Wm2, const float* __restrict__ bm2,
    const float* __restrict__ Wm3, const float* __restrict__ bm3,
    float* __restrict__ out)
{
    int g = blockIdx.x;
    __shared__ float h[HID + EXTRA];
    __shared__ float h1[128];
    __shared__ float h2[64];
    int tid = threadIdx.x;
    h[tid] = emb[(size_t)g * HID + tid];
    h[128 + tid] = emb[(size_t)g * HID + 128 + tid];
    if (tid < EXTRA) h[HID + tid] = fg[(size_t)g * EXTRA + tid];
    __syncthreads();
    float acc = bm1[tid];
    for (int i = 0; i < HID + EXTRA; ++i) acc += h[i] * Wm1[i * 128 + tid];
    h1[tid] = selu_f(acc);
    __syncthreads();
    if (tid < 64) {
        float acc2 = bm2[tid];
        for (int i = 0; i < 128; ++i) acc2 += h1[i] * Wm2[i * 64 + tid];
        h2[tid] = selu_f(acc2);
    }
    __syncthreads();
    if (tid < 64) {
        float p = h2[tid] * Wm3[tid];
        #pragma unroll
        for (int off = 32; off; off >>= 1) p += __shfl_xor(p, off, 64);
        if (tid == 0) out[g] = p + bm3[0];
    }
}

// ---------------- CSR build helpers ----------------
__global__ void count_dst_kernel(const int* __restrict__ dst, int* __restrict__ cnt, int E)
{
    int e = blockIdx.x * 256 + threadIdx.x;
    if (e < E) atomicAdd(&cnt[dst[e]], 1);
}
__global__ void count_gid_kernel(const int* __restrict__ gid, int* __restrict__ cnt, int n)
{
    int i = blockIdx.x * 256 + threadIdx.x;
    if (i < n) atomicAdd(&cnt[gid[i]], 1);
}
__global__ void fill_csr_kernel(const int* __restrict__ src, const int* __restrict__ dst,
                                int* __restrict__ cursor, int* __restrict__ colsrc, int E)
{
    int e = blockIdx.x * 256 + threadIdx.x;
    if (e < E) {
        int p = atomicAdd(&cursor[dst[e]], 1);
        colsrc[p] = src[e];
    }
}

// exclusive scan, 1024 elems/block
__global__ __launch_bounds__(256) void scan_blocks_kernel(
    const int* __restrict__ in, int n, int* __restrict__ out, int* __restrict__ partials)
{
    __shared__ int lds[256];
    int tid = threadIdx.x;
    int base = blockIdx.x * 1024 + tid * 4;
    int v0 = (base + 0 < n) ? in[base + 0] : 0;
    int v1 = (base + 1 < n) ? in[base + 1] : 0;
    int v2 = (base + 2 < n) ? in[base + 2] : 0;
    int v3 = (base + 3 < n) ? in[base + 3] : 0;
    int s = v0 + v1 + v2 + v3;
    lds[tid] = s;
    __syncthreads();
    for (int off = 1; off < 256; off <<= 1) {
        int t = (tid >= off) ? lds[tid - off] : 0;
        __syncthreads();
        lds[tid] += t;
        __syncthreads();
    }
    int excl = lds[tid] - s;
    if (base + 0 < n) out[base + 0] = excl;
    if (base + 1 < n) out[base + 1] = excl + v0;
    if (base + 2 < n) out[base + 2] = excl + v0 + v1;
    if (base + 3 < n) out[base + 3] = excl + v0 + v1 + v2;
    if (tid == 255) partials[blockIdx.x] = lds[255];
}

__global__ __launch_bounds__(256) void scan_partials_kernel(int* partials, int nb)
{
    __shared__ int lds[256];
    int tid = threadIdx.x;
    int v = (tid < nb) ? partials[tid] : 0;
    lds[tid] = v;
    __syncthreads();
    for (int off = 1; off < 256; off <<= 1) {
        int t = (tid >= off) ? lds[tid - off] : 0;
        __syncthreads();
        lds[tid] += t;
        __syncthreads();
    }
    int excl = lds[tid] - v;
    if (tid < nb) partials[tid] = excl;
}

__global__ void add_offsets_kernel(int* __restrict__ out, const int* __restrict__ partials, int n)
{
    int i = blockIdx.x * 256 + threadIdx.x;
    if (i < n) out[i] += partials[i >> 10];
}

// ---------------- launch ----------------
extern "C" void kernel_launch(void* const* d_in, const int* in_sizes, int n_in,
                              void* d_out, int out_size, void* d_ws, size_t ws_size,
                              hipStream_t stream)
{
    const float* feats_node  = (const float*)d_in[0];
    const float* feats_graph = (const float*)d_in[1];
    const float* W1  = (const float*)d_in[2];
    const float* al1 = (const float*)d_in[3];
    const float* ar1 = (const float*)d_in[4];
    const float* b1  = (const float*)d_in[5];
    const float* W2  = (const float*)d_in[6];
    const float* al2 = (const float*)d_in[7];
    const float* ar2 = (const float*)d_in[8];
    const float* b2  = (const float*)d_in[9];
    const float* Ws  = (const float*)d_in[10];
    const float* bs  = (const float*)d_in[11];
    const float* Wm1 = (const float*)d_in[12];
    const float* bm1 = (const float*)d_in[13];
    const float* Wm2 = (const float*)d_in[14];
    const float* bm2 = (const float*)d_in[15];
    const float* Wm3 = (const float*)d_in[16];
    const float* bm3 = (const float*)d_in[17];
    const int* src = (const int*)d_in[18];
    const int* dst = (const int*)d_in[19];
    const int* gid = (const int*)d_in[20];
    float* out = (float*)d_out;
    const int E = in_sizes[18];   // 900000

    // workspace carve-up (256B aligned). Total ~230.8 MB = round-2-proven.
    char* p = (char*)d_ws;
    auto alloc = [&](size_t bytes) {
        char* r = p;
        p += (bytes + 255) & ~(size_t)255;
        return r;
    };
    float* F      = (float*)alloc((size_t)NN * HID * 4);    // 102.4 MB
    float* X      = (float*)alloc((size_t)NN * HID * 4);    // 102.4 MB
    float* el     = (float*)alloc((size_t)NN * HH * 4);
    float* er     = (float*)alloc((size_t)NN * HH * 4);
    float* wbuf   = (float*)alloc((size_t)E * HH * 4);      // 14.4 MB
    float* invden = (float*)alloc((size_t)NN * HH * 4);
    int*   cnt    = (int*)alloc((size_t)(NN + 1) * 4);      // reused as cursor
    int*   rowptr = (int*)alloc((size_t)(NN + 1) * 4);
    int*   colsrc = (int*)alloc((size_t)E * 4);
    int*   gcnt   = (int*)alloc((size_t)(GG + 1) * 4);
    int*   gptr   = (int*)alloc((size_t)(GG + 1) * 4);
    int*   parts  = (int*)alloc(1024 * 4);
    float* emb    = (float*)alloc((size_t)GG * HID * 4);
    u16*   BT1h   = (u16*)alloc((size_t)HID * INF_ * 2);
    u16*   BT1l   = (u16*)alloc((size_t)HID * INF_ * 2);
    u16*   BT2h   = (u16*)alloc((size_t)HID * HID * 2);
    u16*   BT2l   = (u16*)alloc((size_t)HID * HID * 2);

    // ---- CSR over dst ----
    hipMemsetAsync(cnt, 0, (size_t)(NN + 1) * 4, stream);
    count_dst_kernel<<<(E + 255) / 256, 256, 0, stream>>>(dst, cnt, E);
    {
        int n = NN + 1, nb = (n + 1023) / 1024;
        scan_blocks_kernel<<<nb, 256, 0, stream>>>(cnt, n, rowptr, parts);
        scan_partials_kernel<<<1, 256, 0, stream>>>(parts, nb);
        add_offsets_kernel<<<(n + 255) / 256, 256, 0, stream>>>(rowptr, parts, n);
    }
    hipMemcpyAsync(cnt, rowptr, (size_t)(NN + 1) * 4, hipMemcpyDeviceToDevice, stream);
    fill_csr_kernel<<<(E + 255) / 256, 256, 0, stream>>>(src, dst, cnt, colsrc, E);

    // ---- graph ranges (node_gid is sorted) ----
    hipMemsetAsync(gcnt, 0, (size_t)(GG + 1) * 4, stream);
    count_gid_kernel<<<(NN + 255) / 256, 256, 0, stream>>>(gid, gcnt, NN);
    {
        int n = GG + 1, nb = (n + 1023) / 1024;
        scan_blocks_kernel<<<nb, 256, 0, stream>>>(gcnt, n, gptr, parts);
        scan_partials_kernel<<<1, 256, 0, stream>>>(parts, nb);
        add_offsets_kernel<<<(n + 255) / 256, 256, 0, stream>>>(gptr, parts, n);
    }

    // ---- weight conversions ----
    wsplit_kernel<<<(HID * INF_ + 255) / 256, 256, 0, stream>>>(W1, BT1h, BT1l, INF_, 6);
    wsplit_kernel<<<(HID * HID + 255) / 256, 256, 0, stream>>>(W2, BT2h, BT2l, HID, 8);

    dim3 ggrid((NN + 127) / 128, HID / 128);
    const int nh_blocks = (NN * HH + 255) / 256;

    // ---- GAT layer 1 ----
    mfma_gemm_kernel<<<ggrid, 256, 0, stream>>>(feats_node, BT1h, BT1l, F, NN, INF_);
    elr_kernel<<<nh_blocks, 256, 0, stream>>>(F, al1, ar1, el, er);
    edge_softmax_kernel<<<nh_blocks, 256, 0, stream>>>(el, er, rowptr, colsrc, wbuf, invden);
    aggregate_kernel<<<(NN + 3) / 4, 256, 0, stream>>>(F, wbuf, invden, rowptr, colsrc, b1, X);

    // ---- GAT layer 2 ----
    mfma_gemm_kernel<<<ggrid, 256, 0, stream>>>(X, BT2h, BT2l, F, NN, HID);
    elr_kernel<<<nh_blocks, 256, 0, stream>>>(F, al2, ar2, el, er);
    edge_softmax_kernel<<<nh_blocks, 256, 0, stream>>>(el, er, rowptr, colsrc, wbuf, invden);
    aggregate_kernel<<<(NN + 3) / 4, 256, 0, stream>>>(F, wbuf, invden, rowptr, colsrc, b2, X);

    // ---- readout + MLP ----
    readout_kernel<<<(GG + 3) / 4, 256, 0, stream>>>(X, Ws, bs, gptr, emb);
    mlp_kernel<<<GG, 128, 0, stream>>>(emb, feats_graph, Wm1, bm1, Wm2, bm2, Wm3, bm3, out);
}

// Round 7
// 708.041 us; speedup vs baseline: 1.5385x; 1.1354x over previous
//
#include <hip/hip_runtime.h>
#include <hip/hip_bf16.h>
#include <math.h>

// Problem constants (fixed by the reference)
#define NN     100000   // nodes
#define GG     2000     // graphs
#define HH     4        // heads
#define DD     64       // per-head dim
#define HID    256      // H*D
#define INF_   64       // in feats
#define EXTRA  8        // graph feats

typedef unsigned short u16;
typedef __attribute__((ext_vector_type(8))) short bf16x8;
typedef __attribute__((ext_vector_type(4))) float f32x4;

__device__ __forceinline__ u16 f2bf(float f) {
    unsigned u = __float_as_uint(f);
    return (u16)((u + 0x7fffu + ((u >> 16) & 1u)) >> 16);
}
__device__ __forceinline__ float bf2f(u16 v) {
    return __uint_as_float(((unsigned)v) << 16);
}

// ---------------- W [K,256] -> transposed hi/lo bf16 [256,K] ----------------
__global__ __launch_bounds__(256) void wsplit_kernel(
    const float* __restrict__ W, u16* __restrict__ hi, u16* __restrict__ lo,
    int K, int lgK)
{
    int idx = blockIdx.x * 256 + threadIdx.x;   // n*K + k
    if (idx >= 256 * K) return;
    int n = idx >> lgK, k = idx & (K - 1);
    float w = W[k * HID + n];
    u16 h = f2bf(w);
    hi[idx] = h;
    lo[idx] = f2bf(w - bf2f(h));
}

// ---------------- MFMA GEMM, split-split numerics, fused el/er epilogue ------
// C[M,256] = A_f32[M,K] @ B ; A split hi+lo in-register during staging,
// B pre-split (wsplit). 3 MFMAs/frag: Ah*Bh + Al*Bh + Ah*Bl (near-f32).
// PRECISION (rounds 4/5, absmax 130): single-bf16 operands perturb attention
// logits ~0.13 -> ~25% attention-weight error -> fail. Keep split-split.
// el/er computed from the f32 accumulators (each wave owns one head's 64
// cols: h = blockIdx.y*2 + wx) — logits see pre-rounding values, so C may be
// stored bf16 when its only remaining consumer is the message gather.
template<bool BF16_OUT>
__global__ __launch_bounds__(256) void mfma_gemm_kernel(
    const float* __restrict__ A, const u16* __restrict__ BThi,
    const u16* __restrict__ BTlo, float* __restrict__ Cf, u16* __restrict__ Cb,
    const float* __restrict__ al, const float* __restrict__ ar,
    float* __restrict__ el, float* __restrict__ er, int M, int K)
{
    __shared__ __align__(16) u16 Ah[128 * 40];
    __shared__ __align__(16) u16 Al[128 * 40];
    __shared__ __align__(16) u16 Bh[128 * 40];
    __shared__ __align__(16) u16 Bl[128 * 40];
    const int tid  = threadIdx.x;
    const int wave = tid >> 6, lane = tid & 63;
    const int quad = lane >> 4, l15 = lane & 15;
    const int wy = wave >> 1, wx = wave & 1;
    const int r0 = blockIdx.x * 128, c0 = blockIdx.y * 128;
    const int sr = tid >> 2, sseg = tid & 3;

    f32x4 acc[4][4];
    #pragma unroll
    for (int i = 0; i < 4; ++i)
        #pragma unroll
        for (int j = 0; j < 4; ++j)
            acc[i][j] = (f32x4){0.f, 0.f, 0.f, 0.f};

    for (int k0 = 0; k0 < K; k0 += 32) {
        #pragma unroll
        for (int half = 0; half < 2; ++half) {
            int r = sr + half * 64;
            int gr = min(r0 + r, M - 1);
            const float* ap = A + (size_t)gr * K + k0 + sseg * 8;
            float4 va0 = *reinterpret_cast<const float4*>(ap);
            float4 va1 = *reinterpret_cast<const float4*>(ap + 4);
            float av[8] = {va0.x, va0.y, va0.z, va0.w, va1.x, va1.y, va1.z, va1.w};
            bf16x8 vh, vl;
            #pragma unroll
            for (int m = 0; m < 8; ++m) {
                u16 h = f2bf(av[m]);
                vh[m] = (short)h;
                vl[m] = (short)f2bf(av[m] - bf2f(h));
            }
            *reinterpret_cast<bf16x8*>(&Ah[r * 40 + sseg * 8]) = vh;
            *reinterpret_cast<bf16x8*>(&Al[r * 40 + sseg * 8]) = vl;
            int gc = c0 + r;   // < 256 always
            *reinterpret_cast<bf16x8*>(&Bh[r * 40 + sseg * 8]) =
                *reinterpret_cast<const bf16x8*>(BThi + (size_t)gc * K + k0 + sseg * 8);
            *reinterpret_cast<bf16x8*>(&Bl[r * 40 + sseg * 8]) =
                *reinterpret_cast<const bf16x8*>(BTlo + (size_t)gc * K + k0 + sseg * 8);
        }
        __syncthreads();
        bf16x8 afh[4], afl[4], bfh[4], bfl[4];
        #pragma unroll
        for (int i = 0; i < 4; ++i) {
            int row = (wy * 64 + i * 16 + l15) * 40 + quad * 8;
            afh[i] = *reinterpret_cast<const bf16x8*>(&Ah[row]);
            afl[i] = *reinterpret_cast<const bf16x8*>(&Al[row]);
        }
        #pragma unroll
        for (int j = 0; j < 4; ++j) {
            int row = (wx * 64 + j * 16 + l15) * 40 + quad * 8;
            bfh[j] = *reinterpret_cast<const bf16x8*>(&Bh[row]);
            bfl[j] = *reinterpret_cast<const bf16x8*>(&Bl[row]);
        }
        #pragma unroll
        for (int i = 0; i < 4; ++i)
            #pragma unroll
            for (int j = 0; j < 4; ++j) {
                acc[i][j] = __builtin_amdgcn_mfma_f32_16x16x32_bf16(afh[i], bfh[j], acc[i][j], 0, 0, 0);
                acc[i][j] = __builtin_amdgcn_mfma_f32_16x16x32_bf16(afl[i], bfh[j], acc[i][j], 0, 0, 0);
                acc[i][j] = __builtin_amdgcn_mfma_f32_16x16x32_bf16(afh[i], bfl[j], acc[i][j], 0, 0, 0);
            }
        __syncthreads();
    }

    // ---- C store. C/D layout: col = l15, row = quad*4 + rr ----
    #pragma unroll
    for (int i = 0; i < 4; ++i)
        #pragma unroll
        for (int rr = 0; rr < 4; ++rr) {
            int grow = r0 + wy * 64 + i * 16 + quad * 4 + rr;
            if (grow < M) {
                if (BF16_OUT) {
                    u16* crow = Cb + (size_t)grow * HID + c0 + wx * 64 + l15;
                    #pragma unroll
                    for (int j = 0; j < 4; ++j) crow[j * 16] = f2bf(acc[i][j][rr]);
                } else {
                    float* crow = Cf + (size_t)grow * HID + c0 + wx * 64 + l15;
                    #pragma unroll
                    for (int j = 0; j < 4; ++j) crow[j * 16] = acc[i][j][rr];
                }
            }
        }

    // ---- fused el/er from f32 accumulators (one head per wave) ----
    const int h = blockIdx.y * 2 + wx;
    float alf[4], arf[4];
    #pragma unroll
    for (int j = 0; j < 4; ++j) {
        alf[j] = al[h * DD + j * 16 + l15];
        arf[j] = ar[h * DD + j * 16 + l15];
    }
    #pragma unroll
    for (int i = 0; i < 4; ++i)
        #pragma unroll
        for (int rr = 0; rr < 4; ++rr) {
            float sl = acc[i][0][rr] * alf[0] + acc[i][1][rr] * alf[1]
                     + acc[i][2][rr] * alf[2] + acc[i][3][rr] * alf[3];
            float sr_ = acc[i][0][rr] * arf[0] + acc[i][1][rr] * arf[1]
                      + acc[i][2][rr] * arf[2] + acc[i][3][rr] * arf[3];
            #pragma unroll
            for (int off = 1; off < 16; off <<= 1) {
                sl  += __shfl_xor(sl, off, 64);
                sr_ += __shfl_xor(sr_, off, 64);
            }
            if (l15 == 0) {
                int grow = r0 + wy * 64 + i * 16 + quad * 4 + rr;
                if (grow < M) {
                    el[grow * 4 + h] = sl;
                    er[grow * 4 + h] = sr_;
                }
            }
        }
}

__device__ __forceinline__ float leaky02(float x) { return x > 0.f ? x : 0.2f * x; }

// ---------------- edge softmax: one thread per (dst-node, head) ----------------
__global__ __launch_bounds__(256) void edge_softmax_kernel(
    const float* __restrict__ el, const float* __restrict__ er,
    const int* __restrict__ rowptr, const int* __restrict__ colsrc,
    float* __restrict__ w, float* __restrict__ invden)
{
    int idx = blockIdx.x * 256 + threadIdx.x;   // (t,h)
    if (idx >= NN * HH) return;
    int t = idx >> 2, h = idx & 3;
    int beg = rowptr[t], end = rowptr[t + 1];
    float ert = er[idx];
    float m = -1e30f;
    for (int i = beg; i < end; ++i) {
        int s = colsrc[i];
        m = fmaxf(m, leaky02(el[s * 4 + h] + ert));
    }
    float den = 0.f;
    for (int i = beg; i < end; ++i) {
        int s = colsrc[i];
        float v = expf(leaky02(el[s * 4 + h] + ert) - m);
        w[(size_t)i * 4 + h] = v;
        den += v;
    }
    invden[idx] = 1.f / den;   // deg >= 1 (self-loops), den > 0
}

// ---------------- layer-1 aggregate: f32 gather -> f32 out (logit-sensitive) --
__global__ __launch_bounds__(256) void aggregate_f32_kernel(
    const float* __restrict__ F, const float* __restrict__ w,
    const float* __restrict__ invden, const int* __restrict__ rowptr,
    const int* __restrict__ colsrc, const float* __restrict__ bias,
    float* __restrict__ out)
{
    int t = blockIdx.x * 4 + (threadIdx.x >> 6);
    int lane = threadIdx.x & 63;
    if (t >= NN) return;
    int beg = rowptr[t], end = rowptr[t + 1];
    float a0 = 0.f, a1 = 0.f, a2 = 0.f, a3 = 0.f;
    for (int i = beg; i < end; ++i) {
        int s = colsrc[i];
        float4 wv = *reinterpret_cast<const float4*>(w + (size_t)i * 4);
        const float* Fs = F + (size_t)s * HID;
        a0 += wv.x * Fs[lane];
        a1 += wv.y * Fs[64 + lane];
        a2 += wv.z * Fs[128 + lane];
        a3 += wv.w * Fs[192 + lane];
    }
    float4 inv = *reinterpret_cast<const float4*>(invden + (size_t)t * 4);
    float* o = out + (size_t)t * HID;
    o[lane]       = fmaxf(a0 * inv.x + bias[lane], 0.f);
    o[64 + lane]  = fmaxf(a1 * inv.y + bias[64 + lane], 0.f);
    o[128 + lane] = fmaxf(a2 * inv.z + bias[128 + lane], 0.f);
    o[192 + lane] = fmaxf(a3 * inv.w + bias[192 + lane], 0.f);
}

// ---------------- layer-2 aggregate: bf16 gather -> bf16 out ------------------
// X2 feeds only the readout (no logits downstream): bf16 rounding -> emb error
// ~0.002-0.01 -> ~1-3 on the output (threshold margin 8x). Halves gather+write.
__global__ __launch_bounds__(256) void aggregate_bf16_kernel(
    const u16* __restrict__ F, const float* __restrict__ w,
    const float* __restrict__ invden, const int* __restrict__ rowptr,
    const int* __restrict__ colsrc, const float* __restrict__ bias,
    u16* __restrict__ out)
{
    int t = blockIdx.x * 4 + (threadIdx.x >> 6);
    int lane = threadIdx.x & 63;
    if (t >= NN) return;
    int beg = rowptr[t], end = rowptr[t + 1];
    float a0 = 0.f, a1 = 0.f, a2 = 0.f, a3 = 0.f;
    for (int i = beg; i < end; ++i) {
        int s = colsrc[i];
        float4 wv = *reinterpret_cast<const float4*>(w + (size_t)i * 4);
        const u16* Fs = F + (size_t)s * HID;
        a0 += wv.x * bf2f(Fs[lane]);
        a1 += wv.y * bf2f(Fs[64 + lane]);
        a2 += wv.z * bf2f(Fs[128 + lane]);
        a3 += wv.w * bf2f(Fs[192 + lane]);
    }
    float4 inv = *reinterpret_cast<const float4*>(invden + (size_t)t * 4);
    u16* o = out + (size_t)t * HID;
    o[lane]       = f2bf(fmaxf(a0 * inv.x + bias[lane], 0.f));
    o[64 + lane]  = f2bf(fmaxf(a1 * inv.y + bias[64 + lane], 0.f));
    o[128 + lane] = f2bf(fmaxf(a2 * inv.z + bias[128 + lane], 0.f));
    o[192 + lane] = f2bf(fmaxf(a3 * inv.w + bias[192 + lane], 0.f));
}

// ---------------- weighted-average readout (bf16 X): one wave per graph -------
__global__ __launch_bounds__(256) void readout_kernel(
    const u16* __restrict__ X, const float* __restrict__ Ws,
    const float* __restrict__ bs, const int* __restrict__ gptr,
    float* __restrict__ emb)
{
    int g = blockIdx.x * 4 + (threadIdx.x >> 6);
    int lane = threadIdx.x & 63;
    if (g >= GG) return;
    int beg = gptr[g], end = gptr[g + 1];
    float w0 = Ws[lane], w1 = Ws[64 + lane], w2 = Ws[128 + lane], w3 = Ws[192 + lane];
    float b = bs[0];
    float a0 = 0.f, a1 = 0.f, a2 = 0.f, a3 = 0.f, wsum = 0.f;
    for (int n = beg; n < end; ++n) {
        const u16* x = X + (size_t)n * HID;
        float x0 = bf2f(x[lane]), x1 = bf2f(x[64 + lane]);
        float x2 = bf2f(x[128 + lane]), x3 = bf2f(x[192 + lane]);
        float p = x0 * w0 + x1 * w1 + x2 * w2 + x3 * w3;
        #pragma unroll
        for (int off = 32; off; off >>= 1) p += __shfl_xor(p, off, 64);
        float w = 1.f / (1.f + expf(-(p + b)));
        wsum += w;
        a0 += w * x0; a1 += w * x1; a2 += w * x2; a3 += w * x3;
    }
    float inv = (wsum == 0.f) ? 1.f : wsum;
    float* e = emb + (size_t)g * HID;
    e[lane] = a0 / inv; e[64 + lane] = a1 / inv;
    e[128 + lane] = a2 / inv; e[192 + lane] = a3 / inv;
}

__device__ __forceinline__ float selu_f(float x)
{
    const float scale = 1.0507009873554805f, alpha = 1.6732632423543772f;
    return scale * (x > 0.f ? x : alpha * expm1f(x));
}

// ---------------- MLP head: one block (128 thr) per graph ----------------
__global__ __launch_bounds__(128) void mlp_kernel(
    const float* __restrict__ emb, const float* __restrict__ fg,
    const float* __restrict__ Wm1, const float* __restrict__ bm1,
    const float* __restrict__ Wm2, const float* __restrict__ bm2,
    const float* __restrict__ Wm3, const float* __restrict__ bm3,
    float* __restrict__ out)
{
    int g = blockIdx.x;
    __shared__ float h[HID + EXTRA];
    __shared__ float h1[128];
    __shared__ float h2[64];
    int tid = threadIdx.x;
    h[tid] = emb[(size_t)g * HID + tid];
    h[128 + tid] = emb[(size_t)g * HID + 128 + tid];
    if (tid < EXTRA) h[HID + tid] = fg[(size_t)g * EXTRA + tid];
    __syncthreads();
    float acc = bm1[tid];
    for (int i = 0; i < HID + EXTRA; ++i) acc += h[i] * Wm1[i * 128 + tid];
    h1[tid] = selu_f(acc);
    __syncthreads();
    if (tid < 64) {
        float acc2 = bm2[tid];
        for (int i = 0; i < 128; ++i) acc2 += h1[i] * Wm2[i * 64 + tid];
        h2[tid] = selu_f(acc2);
    }
    __syncthreads();
    if (tid < 64) {
        float p = h2[tid] * Wm3[tid];
        #pragma unroll
        for (int off = 32; off; off >>= 1) p += __shfl_xor(p, off, 64);
        if (tid == 0) out[g] = p + bm3[0];
    }
}

// ---------------- CSR build helpers ----------------
__global__ void count_dst_kernel(const int* __restrict__ dst, int* __restrict__ cnt, int E)
{
    int e = blockIdx.x * 256 + threadIdx.x;
    if (e < E) atomicAdd(&cnt[dst[e]], 1);
}
__global__ void count_gid_kernel(const int* __restrict__ gid, int* __restrict__ cnt, int n)
{
    int i = blockIdx.x * 256 + threadIdx.x;
    if (i < n) atomicAdd(&cnt[gid[i]], 1);
}
__global__ void fill_csr_kernel(const int* __restrict__ src, const int* __restrict__ dst,
                                int* __restrict__ cursor, int* __restrict__ colsrc, int E)
{
    int e = blockIdx.x * 256 + threadIdx.x;
    if (e < E) {
        int p = atomicAdd(&cursor[dst[e]], 1);
        colsrc[p] = src[e];
    }
}

// exclusive scan, 1024 elems/block
__global__ __launch_bounds__(256) void scan_blocks_kernel(
    const int* __restrict__ in, int n, int* __restrict__ out, int* __restrict__ partials)
{
    __shared__ int lds[256];
    int tid = threadIdx.x;
    int base = blockIdx.x * 1024 + tid * 4;
    int v0 = (base + 0 < n) ? in[base + 0] : 0;
    int v1 = (base + 1 < n) ? in[base + 1] : 0;
    int v2 = (base + 2 < n) ? in[base + 2] : 0;
    int v3 = (base + 3 < n) ? in[base + 3] : 0;
    int s = v0 + v1 + v2 + v3;
    lds[tid] = s;
    __syncthreads();
    for (int off = 1; off < 256; off <<= 1) {
        int t = (tid >= off) ? lds[tid - off] : 0;
        __syncthreads();
        lds[tid] += t;
        __syncthreads();
    }
    int excl = lds[tid] - s;
    if (base + 0 < n) out[base + 0] = excl;
    if (base + 1 < n) out[base + 1] = excl + v0;
    if (base + 2 < n) out[base + 2] = excl + v0 + v1;
    if (base + 3 < n) out[base + 3] = excl + v0 + v1 + v2;
    if (tid == 255) partials[blockIdx.x] = lds[255];
}

__global__ __launch_bounds__(256) void scan_partials_kernel(int* partials, int nb)
{
    __shared__ int lds[256];
    int tid = threadIdx.x;
    int v = (tid < nb) ? partials[tid] : 0;
    lds[tid] = v;
    __syncthreads();
    for (int off = 1; off < 256; off <<= 1) {
        int t = (tid >= off) ? lds[tid - off] : 0;
        __syncthreads();
        lds[tid] += t;
        __syncthreads();
    }
    int excl = lds[tid] - v;
    if (tid < nb) partials[tid] = excl;
}

__global__ void add_offsets_kernel(int* __restrict__ out, const int* __restrict__ partials, int n)
{
    int i = blockIdx.x * 256 + threadIdx.x;
    if (i < n) out[i] += partials[i >> 10];
}

// ---------------- launch ----------------
extern "C" void kernel_launch(void* const* d_in, const int* in_sizes, int n_in,
                              void* d_out, int out_size, void* d_ws, size_t ws_size,
                              hipStream_t stream)
{
    const float* feats_node  = (const float*)d_in[0];
    const float* feats_graph = (const float*)d_in[1];
    const float* W1  = (const float*)d_in[2];
    const float* al1 = (const float*)d_in[3];
    const float* ar1 = (const float*)d_in[4];
    const float* b1  = (const float*)d_in[5];
    const float* W2  = (const float*)d_in[6];
    const float* al2 = (const float*)d_in[7];
    const float* ar2 = (const float*)d_in[8];
    const float* b2  = (const float*)d_in[9];
    const float* Ws  = (const float*)d_in[10];
    const float* bs  = (const float*)d_in[11];
    const float* Wm1 = (const float*)d_in[12];
    const float* bm1 = (const float*)d_in[13];
    const float* Wm2 = (const float*)d_in[14];
    const float* bm2 = (const float*)d_in[15];
    const float* Wm3 = (const float*)d_in[16];
    const float* bm3 = (const float*)d_in[17];
    const int* src = (const int*)d_in[18];
    const int* dst = (const int*)d_in[19];
    const int* gid = (const int*)d_in[20];
    float* out = (float*)d_out;
    const int E = in_sizes[18];   // 900000

    // workspace carve-up (256B aligned). Total ~230.8 MB = round-2/6-proven.
    char* p = (char*)d_ws;
    auto alloc = [&](size_t bytes) {
        char* r = p;
        p += (bytes + 255) & ~(size_t)255;
        return r;
    };
    float* F      = (float*)alloc((size_t)NN * HID * 4);    // F1 f32; later F2 bf16 (alias)
    float* X      = (float*)alloc((size_t)NN * HID * 4);    // X1 f32; later X2 bf16 (alias)
    float* el     = (float*)alloc((size_t)NN * HH * 4);
    float* er     = (float*)alloc((size_t)NN * HH * 4);
    float* wbuf   = (float*)alloc((size_t)E * HH * 4);      // 14.4 MB
    float* invden = (float*)alloc((size_t)NN * HH * 4);
    int*   cnt    = (int*)alloc((size_t)(NN + 1) * 4);      // reused as cursor
    int*   rowptr = (int*)alloc((size_t)(NN + 1) * 4);
    int*   colsrc = (int*)alloc((size_t)E * 4);
    int*   gcnt   = (int*)alloc((size_t)(GG + 1) * 4);
    int*   gptr   = (int*)alloc((size_t)(GG + 1) * 4);
    int*   parts  = (int*)alloc(1024 * 4);
    float* emb    = (float*)alloc((size_t)GG * HID * 4);
    u16*   BT1h   = (u16*)alloc((size_t)HID * INF_ * 2);
    u16*   BT1l   = (u16*)alloc((size_t)HID * INF_ * 2);
    u16*   BT2h   = (u16*)alloc((size_t)HID * HID * 2);
    u16*   BT2l   = (u16*)alloc((size_t)HID * HID * 2);
    u16*   Fbf2   = (u16*)F;   // alias: F1 dead after aggregate-1
    u16*   Xbf2   = (u16*)X;   // alias: X1 dead after gemm2 consumed it

    // ---- CSR over dst ----
    hipMemsetAsync(cnt, 0, (size_t)(NN + 1) * 4, stream);
    count_dst_kernel<<<(E + 255) / 256, 256, 0, stream>>>(dst, cnt, E);
    {
        int n = NN + 1, nb = (n + 1023) / 1024;
        scan_blocks_kernel<<<nb, 256, 0, stream>>>(cnt, n, rowptr, parts);
        scan_partials_kernel<<<1, 256, 0, stream>>>(parts, nb);
        add_offsets_kernel<<<(n + 255) / 256, 256, 0, stream>>>(rowptr, parts, n);
    }
    hipMemcpyAsync(cnt, rowptr, (size_t)(NN + 1) * 4, hipMemcpyDeviceToDevice, stream);
    fill_csr_kernel<<<(E + 255) / 256, 256, 0, stream>>>(src, dst, cnt, colsrc, E);

    // ---- graph ranges (node_gid is sorted) ----
    hipMemsetAsync(gcnt, 0, (size_t)(GG + 1) * 4, stream);
    count_gid_kernel<<<(NN + 255) / 256, 256, 0, stream>>>(gid, gcnt, NN);
    {
        int n = GG + 1, nb = (n + 1023) / 1024;
        scan_blocks_kernel<<<nb, 256, 0, stream>>>(gcnt, n, gptr, parts);
        scan_partials_kernel<<<1, 256, 0, stream>>>(parts, nb);
        add_offsets_kernel<<<(n + 255) / 256, 256, 0, stream>>>(gptr, parts, n);
    }

    // ---- weight conversions ----
    wsplit_kernel<<<(HID * INF_ + 255) / 256, 256, 0, stream>>>(W1, BT1h, BT1l, INF_, 6);
    wsplit_kernel<<<(HID * HID + 255) / 256, 256, 0, stream>>>(W2, BT2h, BT2l, HID, 8);

    dim3 ggrid((NN + 127) / 128, HID / 128);
    const int nh_blocks = (NN * HH + 255) / 256;

    // ---- GAT layer 1 (f32 message path: feeds layer-2 logits) ----
    mfma_gemm_kernel<false><<<ggrid, 256, 0, stream>>>(
        feats_node, BT1h, BT1l, F, nullptr, al1, ar1, el, er, NN, INF_);
    edge_softmax_kernel<<<nh_blocks, 256, 0, stream>>>(el, er, rowptr, colsrc, wbuf, invden);
    aggregate_f32_kernel<<<(NN + 3) / 4, 256, 0, stream>>>(F, wbuf, invden, rowptr, colsrc, b1, X);

    // ---- GAT layer 2 (bf16 message path: feeds readout only) ----
    mfma_gemm_kernel<true><<<ggrid, 256, 0, stream>>>(
        X, BT2h, BT2l, nullptr, Fbf2, al2, ar2, el, er, NN, HID);
    edge_softmax_kernel<<<nh_blocks, 256, 0, stream>>>(el, er, rowptr, colsrc, wbuf, invden);
    aggregate_bf16_kernel<<<(NN + 3) / 4, 256, 0, stream>>>(Fbf2, wbuf, invden, rowptr, colsrc,
                                                            b2, Xbf2);

    // ---- readout + MLP ----
    readout_kernel<<<(GG + 3) / 4, 256, 0, stream>>>(Xbf2, Ws, bs, gptr, emb);
    mlp_kernel<<<GG, 128, 0, stream>>>(emb, feats_graph, Wm1, bm1, Wm2, bm2, Wm3, bm3, out);
}

// Round 8
// 671.616 us; speedup vs baseline: 1.6219x; 1.0542x over previous
//
#include <hip/hip_runtime.h>
#include <hip/hip_bf16.h>
#include <math.h>

// Problem constants (fixed by the reference)
#define NN     100000   // nodes
#define GG     2000     // graphs
#define HH     4        // heads
#define DD     64       // per-head dim
#define HID    256      // H*D
#define INF_   64       // in feats
#define EXTRA  8        // graph feats

typedef unsigned short u16;
typedef __attribute__((ext_vector_type(8))) short bf16x8;
typedef __attribute__((ext_vector_type(4))) float f32x4;

__device__ __forceinline__ u16 f2bf(float f) {
    unsigned u = __float_as_uint(f);
    return (u16)((u + 0x7fffu + ((u >> 16) & 1u)) >> 16);
}
__device__ __forceinline__ float bf2f(u16 v) {
    return __uint_as_float(((unsigned)v) << 16);
}

// ---------------- W [K,256] -> transposed hi/lo bf16 [256,K] ----------------
__global__ __launch_bounds__(256) void wsplit_kernel(
    const float* __restrict__ W, u16* __restrict__ hi, u16* __restrict__ lo,
    int K, int lgK)
{
    int idx = blockIdx.x * 256 + threadIdx.x;   // n*K + k
    if (idx >= 256 * K) return;
    int n = idx >> lgK, k = idx & (K - 1);
    float w = W[k * HID + n];
    u16 h = f2bf(w);
    hi[idx] = h;
    lo[idx] = f2bf(w - bf2f(h));
}

// ---------------- MFMA GEMM, split-split numerics, fused el/er epilogue ------
// C[M,256] = A_f32[M,K] @ B ; A split hi+lo in-register during staging,
// B pre-split (wsplit). 3 MFMAs/frag: Ah*Bh + Al*Bh + Ah*Bl (near-f32).
// PRECISION (rounds 4/5, absmax 130): single-bf16 operands perturb attention
// logits ~0.13 -> ~25% attention-weight error -> fail. Keep split-split.
// el/er computed from the f32 accumulators (each wave owns one head's 64
// cols: h = blockIdx.y*2 + wx) — logits see pre-rounding values, so C may be
// stored bf16 when its only remaining consumer is the message gather.
template<bool BF16_OUT>
__global__ __launch_bounds__(256) void mfma_gemm_kernel(
    const float* __restrict__ A, const u16* __restrict__ BThi,
    const u16* __restrict__ BTlo, float* __restrict__ Cf, u16* __restrict__ Cb,
    const float* __restrict__ al, const float* __restrict__ ar,
    float* __restrict__ el, float* __restrict__ er, int M, int K)
{
    __shared__ __align__(16) u16 Ah[128 * 40];
    __shared__ __align__(16) u16 Al[128 * 40];
    __shared__ __align__(16) u16 Bh[128 * 40];
    __shared__ __align__(16) u16 Bl[128 * 40];
    const int tid  = threadIdx.x;
    const int wave = tid >> 6, lane = tid & 63;
    const int quad = lane >> 4, l15 = lane & 15;
    const int wy = wave >> 1, wx = wave & 1;
    const int r0 = blockIdx.x * 128, c0 = blockIdx.y * 128;
    const int sr = tid >> 2, sseg = tid & 3;

    f32x4 acc[4][4];
    #pragma unroll
    for (int i = 0; i < 4; ++i)
        #pragma unroll
        for (int j = 0; j < 4; ++j)
            acc[i][j] = (f32x4){0.f, 0.f, 0.f, 0.f};

    for (int k0 = 0; k0 < K; k0 += 32) {
        #pragma unroll
        for (int half = 0; half < 2; ++half) {
            int r = sr + half * 64;
            int gr = min(r0 + r, M - 1);
            const float* ap = A + (size_t)gr * K + k0 + sseg * 8;
            float4 va0 = *reinterpret_cast<const float4*>(ap);
            float4 va1 = *reinterpret_cast<const float4*>(ap + 4);
            float av[8] = {va0.x, va0.y, va0.z, va0.w, va1.x, va1.y, va1.z, va1.w};
            bf16x8 vh, vl;
            #pragma unroll
            for (int m = 0; m < 8; ++m) {
                u16 h = f2bf(av[m]);
                vh[m] = (short)h;
                vl[m] = (short)f2bf(av[m] - bf2f(h));
            }
            *reinterpret_cast<bf16x8*>(&Ah[r * 40 + sseg * 8]) = vh;
            *reinterpret_cast<bf16x8*>(&Al[r * 40 + sseg * 8]) = vl;
            int gc = c0 + r;   // < 256 always
            *reinterpret_cast<bf16x8*>(&Bh[r * 40 + sseg * 8]) =
                *reinterpret_cast<const bf16x8*>(BThi + (size_t)gc * K + k0 + sseg * 8);
            *reinterpret_cast<bf16x8*>(&Bl[r * 40 + sseg * 8]) =
                *reinterpret_cast<const bf16x8*>(BTlo + (size_t)gc * K + k0 + sseg * 8);
        }
        __syncthreads();
        bf16x8 afh[4], afl[4], bfh[4], bfl[4];
        #pragma unroll
        for (int i = 0; i < 4; ++i) {
            int row = (wy * 64 + i * 16 + l15) * 40 + quad * 8;
            afh[i] = *reinterpret_cast<const bf16x8*>(&Ah[row]);
            afl[i] = *reinterpret_cast<const bf16x8*>(&Al[row]);
        }
        #pragma unroll
        for (int j = 0; j < 4; ++j) {
            int row = (wx * 64 + j * 16 + l15) * 40 + quad * 8;
            bfh[j] = *reinterpret_cast<const bf16x8*>(&Bh[row]);
            bfl[j] = *reinterpret_cast<const bf16x8*>(&Bl[row]);
        }
        #pragma unroll
        for (int i = 0; i < 4; ++i)
            #pragma unroll
            for (int j = 0; j < 4; ++j) {
                acc[i][j] = __builtin_amdgcn_mfma_f32_16x16x32_bf16(afh[i], bfh[j], acc[i][j], 0, 0, 0);
                acc[i][j] = __builtin_amdgcn_mfma_f32_16x16x32_bf16(afl[i], bfh[j], acc[i][j], 0, 0, 0);
                acc[i][j] = __builtin_amdgcn_mfma_f32_16x16x32_bf16(afh[i], bfl[j], acc[i][j], 0, 0, 0);
            }
        __syncthreads();
    }

    // ---- C store. C/D layout: col = l15, row = quad*4 + rr ----
    #pragma unroll
    for (int i = 0; i < 4; ++i)
        #pragma unroll
        for (int rr = 0; rr < 4; ++rr) {
            int grow = r0 + wy * 64 + i * 16 + quad * 4 + rr;
            if (grow < M) {
                if (BF16_OUT) {
                    u16* crow = Cb + (size_t)grow * HID + c0 + wx * 64 + l15;
                    #pragma unroll
                    for (int j = 0; j < 4; ++j) crow[j * 16] = f2bf(acc[i][j][rr]);
                } else {
                    float* crow = Cf + (size_t)grow * HID + c0 + wx * 64 + l15;
                    #pragma unroll
                    for (int j = 0; j < 4; ++j) crow[j * 16] = acc[i][j][rr];
                }
            }
        }

    // ---- fused el/er from f32 accumulators (one head per wave) ----
    const int h = blockIdx.y * 2 + wx;
    float alf[4], arf[4];
    #pragma unroll
    for (int j = 0; j < 4; ++j) {
        alf[j] = al[h * DD + j * 16 + l15];
        arf[j] = ar[h * DD + j * 16 + l15];
    }
    #pragma unroll
    for (int i = 0; i < 4; ++i)
        #pragma unroll
        for (int rr = 0; rr < 4; ++rr) {
            float sl = acc[i][0][rr] * alf[0] + acc[i][1][rr] * alf[1]
                     + acc[i][2][rr] * alf[2] + acc[i][3][rr] * alf[3];
            float sr_ = acc[i][0][rr] * arf[0] + acc[i][1][rr] * arf[1]
                      + acc[i][2][rr] * arf[2] + acc[i][3][rr] * arf[3];
            #pragma unroll
            for (int off = 1; off < 16; off <<= 1) {
                sl  += __shfl_xor(sl, off, 64);
                sr_ += __shfl_xor(sr_, off, 64);
            }
            if (l15 == 0) {
                int grow = r0 + wy * 64 + i * 16 + quad * 4 + rr;
                if (grow < M) {
                    el[grow * 4 + h] = sl;
                    er[grow * 4 + h] = sr_;
                }
            }
        }
}

__device__ __forceinline__ float leaky02(float x) { return x > 0.f ? x : 0.2f * x; }

// ---------------- edge softmax: one thread per (dst-node, head) ----------------
__global__ __launch_bounds__(256) void edge_softmax_kernel(
    const float* __restrict__ el, const float* __restrict__ er,
    const int* __restrict__ rowptr, const int* __restrict__ colsrc,
    float* __restrict__ w, float* __restrict__ invden)
{
    int idx = blockIdx.x * 256 + threadIdx.x;   // (t,h)
    if (idx >= NN * HH) return;
    int t = idx >> 2, h = idx & 3;
    int beg = rowptr[t], end = rowptr[t + 1];
    float ert = er[idx];
    float m = -1e30f;
    for (int i = beg; i < end; ++i) {
        int s = colsrc[i];
        m = fmaxf(m, leaky02(el[s * 4 + h] + ert));
    }
    float den = 0.f;
    for (int i = beg; i < end; ++i) {
        int s = colsrc[i];
        float v = expf(leaky02(el[s * 4 + h] + ert) - m);
        w[(size_t)i * 4 + h] = v;
        den += v;
    }
    invden[idx] = 1.f / den;   // deg >= 1 (self-loops), den > 0
}

// ---------------- layer-1 aggregate: f32 gather -> f32 out (logit-sensitive) --
// Lane l owns row elements 4l..4l+3: ONE dwordx4 per edge per lane (full 1KB
// row in a single VMEM instr), head = l>>4 (uniform per 16-lane group).
// Edge loop unrolled x2 with independent accumulators for MLP.
__global__ __launch_bounds__(256) void aggregate_f32_kernel(
    const float* __restrict__ F, const float* __restrict__ w,
    const float* __restrict__ invden, const int* __restrict__ rowptr,
    const int* __restrict__ colsrc, const float* __restrict__ bias,
    float* __restrict__ out)
{
    int t = blockIdx.x * 4 + (threadIdx.x >> 6);
    int lane = threadIdx.x & 63;
    if (t >= NN) return;
    int beg = rowptr[t], end = rowptr[t + 1];
    const int h = lane >> 4;
    float4 acc0 = make_float4(0.f, 0.f, 0.f, 0.f);
    float4 acc1 = make_float4(0.f, 0.f, 0.f, 0.f);
    int i = beg;
    for (; i + 1 < end; i += 2) {
        int s0 = colsrc[i], s1 = colsrc[i + 1];
        float w0 = w[(size_t)i * 4 + h];
        float w1 = w[(size_t)(i + 1) * 4 + h];
        float4 f0 = *reinterpret_cast<const float4*>(F + (size_t)s0 * HID + 4 * lane);
        float4 f1 = *reinterpret_cast<const float4*>(F + (size_t)s1 * HID + 4 * lane);
        acc0.x += w0 * f0.x; acc0.y += w0 * f0.y; acc0.z += w0 * f0.z; acc0.w += w0 * f0.w;
        acc1.x += w1 * f1.x; acc1.y += w1 * f1.y; acc1.z += w1 * f1.z; acc1.w += w1 * f1.w;
    }
    if (i < end) {
        int s0 = colsrc[i];
        float w0 = w[(size_t)i * 4 + h];
        float4 f0 = *reinterpret_cast<const float4*>(F + (size_t)s0 * HID + 4 * lane);
        acc0.x += w0 * f0.x; acc0.y += w0 * f0.y; acc0.z += w0 * f0.z; acc0.w += w0 * f0.w;
    }
    float inv = invden[t * 4 + h];
    float4 bv = *reinterpret_cast<const float4*>(bias + 4 * lane);
    float4 r;
    r.x = fmaxf((acc0.x + acc1.x) * inv + bv.x, 0.f);
    r.y = fmaxf((acc0.y + acc1.y) * inv + bv.y, 0.f);
    r.z = fmaxf((acc0.z + acc1.z) * inv + bv.z, 0.f);
    r.w = fmaxf((acc0.w + acc1.w) * inv + bv.w, 0.f);
    *reinterpret_cast<float4*>(out + (size_t)t * HID + 4 * lane) = r;
}

// ---------------- layer-2 aggregate: bf16 gather -> bf16 out ------------------
// X2 feeds only the readout (no logits downstream): bf16 rounding -> ~+20 on
// absmax (measured round 7: 24 vs f32's 4; threshold 33.76). Halves traffic.
// Lane l owns elements 4l..4l+3: one 8B ushort4 per edge per lane (512B row
// in one VMEM instr).
__global__ __launch_bounds__(256) void aggregate_bf16_kernel(
    const u16* __restrict__ F, const float* __restrict__ w,
    const float* __restrict__ invden, const int* __restrict__ rowptr,
    const int* __restrict__ colsrc, const float* __restrict__ bias,
    u16* __restrict__ out)
{
    int t = blockIdx.x * 4 + (threadIdx.x >> 6);
    int lane = threadIdx.x & 63;
    if (t >= NN) return;
    int beg = rowptr[t], end = rowptr[t + 1];
    const int h = lane >> 4;
    float4 acc0 = make_float4(0.f, 0.f, 0.f, 0.f);
    float4 acc1 = make_float4(0.f, 0.f, 0.f, 0.f);
    int i = beg;
    for (; i + 1 < end; i += 2) {
        int s0 = colsrc[i], s1 = colsrc[i + 1];
        float w0 = w[(size_t)i * 4 + h];
        float w1 = w[(size_t)(i + 1) * 4 + h];
        ushort4 f0 = *reinterpret_cast<const ushort4*>(F + (size_t)s0 * HID + 4 * lane);
        ushort4 f1 = *reinterpret_cast<const ushort4*>(F + (size_t)s1 * HID + 4 * lane);
        acc0.x += w0 * bf2f(f0.x); acc0.y += w0 * bf2f(f0.y);
        acc0.z += w0 * bf2f(f0.z); acc0.w += w0 * bf2f(f0.w);
        acc1.x += w1 * bf2f(f1.x); acc1.y += w1 * bf2f(f1.y);
        acc1.z += w1 * bf2f(f1.z); acc1.w += w1 * bf2f(f1.w);
    }
    if (i < end) {
        int s0 = colsrc[i];
        float w0 = w[(size_t)i * 4 + h];
        ushort4 f0 = *reinterpret_cast<const ushort4*>(F + (size_t)s0 * HID + 4 * lane);
        acc0.x += w0 * bf2f(f0.x); acc0.y += w0 * bf2f(f0.y);
        acc0.z += w0 * bf2f(f0.z); acc0.w += w0 * bf2f(f0.w);
    }
    float inv = invden[t * 4 + h];
    float4 bv = *reinterpret_cast<const float4*>(bias + 4 * lane);
    ushort4 r;
    r.x = f2bf(fmaxf((acc0.x + acc1.x) * inv + bv.x, 0.f));
    r.y = f2bf(fmaxf((acc0.y + acc1.y) * inv + bv.y, 0.f));
    r.z = f2bf(fmaxf((acc0.z + acc1.z) * inv + bv.z, 0.f));
    r.w = f2bf(fmaxf((acc0.w + acc1.w) * inv + bv.w, 0.f));
    *reinterpret_cast<ushort4*>(out + (size_t)t * HID + 4 * lane) = r;
}

// ---------------- weighted-average readout (bf16 X): one wave per graph -------
__global__ __launch_bounds__(256) void readout_kernel(
    const u16* __restrict__ X, const float* __restrict__ Ws,
    const float* __restrict__ bs, const int* __restrict__ gptr,
    float* __restrict__ emb)
{
    int g = blockIdx.x * 4 + (threadIdx.x >> 6);
    int lane = threadIdx.x & 63;
    if (g >= GG) return;
    int beg = gptr[g], end = gptr[g + 1];
    float4 wv = *reinterpret_cast<const float4*>(Ws + 4 * lane);
    float b = bs[0];
    float4 acc = make_float4(0.f, 0.f, 0.f, 0.f);
    float wsum = 0.f;
    for (int n = beg; n < end; ++n) {
        ushort4 xv = *reinterpret_cast<const ushort4*>(X + (size_t)n * HID + 4 * lane);
        float x0 = bf2f(xv.x), x1 = bf2f(xv.y), x2 = bf2f(xv.z), x3 = bf2f(xv.w);
        float p = x0 * wv.x + x1 * wv.y + x2 * wv.z + x3 * wv.w;
        #pragma unroll
        for (int off = 32; off; off >>= 1) p += __shfl_xor(p, off, 64);
        float w = 1.f / (1.f + expf(-(p + b)));
        wsum += w;
        acc.x += w * x0; acc.y += w * x1; acc.z += w * x2; acc.w += w * x3;
    }
    float inv = (wsum == 0.f) ? 1.f : wsum;
    float4 e;
    e.x = acc.x / inv; e.y = acc.y / inv; e.z = acc.z / inv; e.w = acc.w / inv;
    *reinterpret_cast<float4*>(emb + (size_t)g * HID + 4 * lane) = e;
}

__device__ __forceinline__ float selu_f(float x)
{
    const float scale = 1.0507009873554805f, alpha = 1.6732632423543772f;
    return scale * (x > 0.f ? x : alpha * expm1f(x));
}

// ---------------- MLP head: one block (128 thr) per graph ----------------
__global__ __launch_bounds__(128) void mlp_kernel(
    const float* __restrict__ emb, const float* __restrict__ fg,
    const float* __restrict__ Wm1, const float* __restrict__ bm1,
    const float* __restrict__ Wm2, const float* __restrict__ bm2,
    const float* __restrict__ Wm3, const float* __restrict__ bm3,
    float* __restrict__ out)
{
    int g = blockIdx.x;
    __shared__ float h[HID + EXTRA];
    __shared__ float h1[128];
    __shared__ float h2[64];
    int tid = threadIdx.x;
    h[tid] = emb[(size_t)g * HID + tid];
    h[128 + tid] = emb[(size_t)g * HID + 128 + tid];
    if (tid < EXTRA) h[HID + tid] = fg[(size_t)g * EXTRA + tid];
    __syncthreads();
    float acc = bm1[tid];
    for (int i = 0; i < HID + EXTRA; ++i) acc += h[i] * Wm1[i * 128 + tid];
    h1[tid] = selu_f(acc);
    __syncthreads();
    if (tid < 64) {
        float acc2 = bm2[tid];
        for (int i = 0; i < 128; ++i) acc2 += h1[i] * Wm2[i * 64 + tid];
        h2[tid] = selu_f(acc2);
    }
    __syncthreads();
    if (tid < 64) {
        float p = h2[tid] * Wm3[tid];
        #pragma unroll
        for (int off = 32; off; off >>= 1) p += __shfl_xor(p, off, 64);
        if (tid == 0) out[g] = p + bm3[0];
    }
}

// ---------------- CSR build helpers ----------------
__global__ void count_dst_kernel(const int* __restrict__ dst, int* __restrict__ cnt, int E)
{
    int e = blockIdx.x * 256 + threadIdx.x;
    if (e < E) atomicAdd(&cnt[dst[e]], 1);
}
__global__ void count_gid_kernel(const int* __restrict__ gid, int* __restrict__ cnt, int n)
{
    int i = blockIdx.x * 256 + threadIdx.x;
    if (i < n) atomicAdd(&cnt[gid[i]], 1);
}
__global__ void fill_csr_kernel(const int* __restrict__ src, const int* __restrict__ dst,
                                int* __restrict__ cursor, int* __restrict__ colsrc, int E)
{
    int e = blockIdx.x * 256 + threadIdx.x;
    if (e < E) {
        int p = atomicAdd(&cursor[dst[e]], 1);
        colsrc[p] = src[e];
    }
}

// exclusive scan, 1024 elems/block
__global__ __launch_bounds__(256) void scan_blocks_kernel(
    const int* __restrict__ in, int n, int* __restrict__ out, int* __restrict__ partials)
{
    __shared__ int lds[256];
    int tid = threadIdx.x;
    int base = blockIdx.x * 1024 + tid * 4;
    int v0 = (base + 0 < n) ? in[base + 0] : 0;
    int v1 = (base + 1 < n) ? in[base + 1] : 0;
    int v2 = (base + 2 < n) ? in[base + 2] : 0;
    int v3 = (base + 3 < n) ? in[base + 3] : 0;
    int s = v0 + v1 + v2 + v3;
    lds[tid] = s;
    __syncthreads();
    for (int off = 1; off < 256; off <<= 1) {
        int t = (tid >= off) ? lds[tid - off] : 0;
        __syncthreads();
        lds[tid] += t;
        __syncthreads();
    }
    int excl = lds[tid] - s;
    if (base + 0 < n) out[base + 0] = excl;
    if (base + 1 < n) out[base + 1] = excl + v0;
    if (base + 2 < n) out[base + 2] = excl + v0 + v1;
    if (base + 3 < n) out[base + 3] = excl + v0 + v1 + v2;
    if (tid == 255) partials[blockIdx.x] = lds[255];
}

__global__ __launch_bounds__(256) void scan_partials_kernel(int* partials, int nb)
{
    __shared__ int lds[256];
    int tid = threadIdx.x;
    int v = (tid < nb) ? partials[tid] : 0;
    lds[tid] = v;
    __syncthreads();
    for (int off = 1; off < 256; off <<= 1) {
        int t = (tid >= off) ? lds[tid - off] : 0;
        __syncthreads();
        lds[tid] += t;
        __syncthreads();
    }
    int excl = lds[tid] - v;
    if (tid < nb) partials[tid] = excl;
}

__global__ void add_offsets_kernel(int* __restrict__ out, const int* __restrict__ partials, int n)
{
    int i = blockIdx.x * 256 + threadIdx.x;
    if (i < n) out[i] += partials[i >> 10];
}

// ---------------- launch ----------------
extern "C" void kernel_launch(void* const* d_in, const int* in_sizes, int n_in,
                              void* d_out, int out_size, void* d_ws, size_t ws_size,
                              hipStream_t stream)
{
    const float* feats_node  = (const float*)d_in[0];
    const float* feats_graph = (const float*)d_in[1];
    const float* W1  = (const float*)d_in[2];
    const float* al1 = (const float*)d_in[3];
    const float* ar1 = (const float*)d_in[4];
    const float* b1  = (const float*)d_in[5];
    const float* W2  = (const float*)d_in[6];
    const float* al2 = (const float*)d_in[7];
    const float* ar2 = (const float*)d_in[8];
    const float* b2  = (const float*)d_in[9];
    const float* Ws  = (const float*)d_in[10];
    const float* bs  = (const float*)d_in[11];
    const float* Wm1 = (const float*)d_in[12];
    const float* bm1 = (const float*)d_in[13];
    const float* Wm2 = (const float*)d_in[14];
    const float* bm2 = (const float*)d_in[15];
    const float* Wm3 = (const float*)d_in[16];
    const float* bm3 = (const float*)d_in[17];
    const int* src = (const int*)d_in[18];
    const int* dst = (const int*)d_in[19];
    const int* gid = (const int*)d_in[20];
    float* out = (float*)d_out;
    const int E = in_sizes[18];   // 900000

    // workspace carve-up (256B aligned). Total ~230.8 MB = round-2/6-proven.
    char* p = (char*)d_ws;
    auto alloc = [&](size_t bytes) {
        char* r = p;
        p += (bytes + 255) & ~(size_t)255;
        return r;
    };
    float* F      = (float*)alloc((size_t)NN * HID * 4);    // F1 f32; later F2 bf16 (alias)
    float* X      = (float*)alloc((size_t)NN * HID * 4);    // X1 f32; later X2 bf16 (alias)
    float* el     = (float*)alloc((size_t)NN * HH * 4);
    float* er     = (float*)alloc((size_t)NN * HH * 4);
    float* wbuf   = (float*)alloc((size_t)E * HH * 4);      // 14.4 MB
    float* invden = (float*)alloc((size_t)NN * HH * 4);
    int*   cnt    = (int*)alloc((size_t)(NN + 1) * 4);      // reused as cursor
    int*   rowptr = (int*)alloc((size_t)(NN + 1) * 4);
    int*   colsrc = (int*)alloc((size_t)E * 4);
    int*   gcnt   = (int*)alloc((size_t)(GG + 1) * 4);
    int*   gptr   = (int*)alloc((size_t)(GG + 1) * 4);
    int*   parts  = (int*)alloc(1024 * 4);
    float* emb    = (float*)alloc((size_t)GG * HID * 4);
    u16*   BT1h   = (u16*)alloc((size_t)HID * INF_ * 2);
    u16*   BT1l   = (u16*)alloc((size_t)HID * INF_ * 2);
    u16*   BT2h   = (u16*)alloc((size_t)HID * HID * 2);
    u16*   BT2l   = (u16*)alloc((size_t)HID * HID * 2);
    u16*   Fbf2   = (u16*)F;   // alias: F1 dead after aggregate-1
    u16*   Xbf2   = (u16*)X;   // alias: X1 dead after gemm2 consumed it

    // ---- CSR over dst ----
    hipMemsetAsync(cnt, 0, (size_t)(NN + 1) * 4, stream);
    count_dst_kernel<<<(E + 255) / 256, 256, 0, stream>>>(dst, cnt, E);
    {
        int n = NN + 1, nb = (n + 1023) / 1024;
        scan_blocks_kernel<<<nb, 256, 0, stream>>>(cnt, n, rowptr, parts);
        scan_partials_kernel<<<1, 256, 0, stream>>>(parts, nb);
        add_offsets_kernel<<<(n + 255) / 256, 256, 0, stream>>>(rowptr, parts, n);
    }
    hipMemcpyAsync(cnt, rowptr, (size_t)(NN + 1) * 4, hipMemcpyDeviceToDevice, stream);
    fill_csr_kernel<<<(E + 255) / 256, 256, 0, stream>>>(src, dst, cnt, colsrc, E);

    // ---- graph ranges (node_gid is sorted) ----
    hipMemsetAsync(gcnt, 0, (size_t)(GG + 1) * 4, stream);
    count_gid_kernel<<<(NN + 255) / 256, 256, 0, stream>>>(gid, gcnt, NN);
    {
        int n = GG + 1, nb = (n + 1023) / 1024;
        scan_blocks_kernel<<<nb, 256, 0, stream>>>(gcnt, n, gptr, parts);
        scan_partials_kernel<<<1, 256, 0, stream>>>(parts, nb);
        add_offsets_kernel<<<(n + 255) / 256, 256, 0, stream>>>(gptr, parts, n);
    }

    // ---- weight conversions ----
    wsplit_kernel<<<(HID * INF_ + 255) / 256, 256, 0, stream>>>(W1, BT1h, BT1l, INF_, 6);
    wsplit_kernel<<<(HID * HID + 255) / 256, 256, 0, stream>>>(W2, BT2h, BT2l, HID, 8);

    dim3 ggrid((NN + 127) / 128, HID / 128);
    const int nh_blocks = (NN * HH + 255) / 256;

    // ---- GAT layer 1 (f32 message path: feeds layer-2 logits) ----
    mfma_gemm_kernel<false><<<ggrid, 256, 0, stream>>>(
        feats_node, BT1h, BT1l, F, nullptr, al1, ar1, el, er, NN, INF_);
    edge_softmax_kernel<<<nh_blocks, 256, 0, stream>>>(el, er, rowptr, colsrc, wbuf, invden);
    aggregate_f32_kernel<<<(NN + 3) / 4, 256, 0, stream>>>(F, wbuf, invden, rowptr, colsrc, b1, X);

    // ---- GAT layer 2 (bf16 message path: feeds readout only) ----
    mfma_gemm_kernel<true><<<ggrid, 256, 0, stream>>>(
        X, BT2h, BT2l, nullptr, Fbf2, al2, ar2, el, er, NN, HID);
    edge_softmax_kernel<<<nh_blocks, 256, 0, stream>>>(el, er, rowptr, colsrc, wbuf, invden);
    aggregate_bf16_kernel<<<(NN + 3) / 4, 256, 0, stream>>>(Fbf2, wbuf, invden, rowptr, colsrc,
                                                            b2, Xbf2);

    // ---- readout + MLP ----
    readout_kernel<<<(GG + 3) / 4, 256, 0, stream>>>(Xbf2, Ws, bs, gptr, emb);
    mlp_kernel<<<GG, 128, 0, stream>>>(emb, feats_graph, Wm1, bm1, Wm2, bm2, Wm3, bm3, out);
}

// Round 9
// 645.449 us; speedup vs baseline: 1.6877x; 1.0405x over previous
//
#include <hip/hip_runtime.h>
#include <hip/hip_bf16.h>
#include <math.h>

// Problem constants (fixed by the reference)
#define NN     100000   // nodes
#define GG     2000     // graphs
#define HH     4        // heads
#define DD     64       // per-head dim
#define HID    256      // H*D
#define INF_   64       // in feats
#define EXTRA  8        // graph feats

typedef unsigned short u16;
typedef __attribute__((ext_vector_type(8))) short bf16x8;
typedef __attribute__((ext_vector_type(4))) float f32x4;

__device__ __forceinline__ u16 f2bf(float f) {
    unsigned u = __float_as_uint(f);
    return (u16)((u + 0x7fffu + ((u >> 16) & 1u)) >> 16);
}
__device__ __forceinline__ float bf2f(u16 v) {
    return __uint_as_float(((unsigned)v) << 16);
}

// ---------------- W [K,256] -> transposed hi/lo bf16 [256,K] ----------------
__global__ __launch_bounds__(256) void wsplit_kernel(
    const float* __restrict__ W, u16* __restrict__ hi, u16* __restrict__ lo,
    int K, int lgK)
{
    int idx = blockIdx.x * 256 + threadIdx.x;   // n*K + k
    if (idx >= 256 * K) return;
    int n = idx >> lgK, k = idx & (K - 1);
    float w = W[k * HID + n];
    u16 h = f2bf(w);
    hi[idx] = h;
    lo[idx] = f2bf(w - bf2f(h));
}

// ---------------- wal/war precompute: wal[d][h] = sum_c W1[d][h*64+c]*al[h][c]
__global__ __launch_bounds__(256) void walprep_kernel(
    const float* __restrict__ W1, const float* __restrict__ al,
    const float* __restrict__ ar, float* __restrict__ wal, float* __restrict__ war)
{
    int tid = threadIdx.x;          // 256 = 64 d x 4 h
    int d = tid >> 2, h = tid & 3;
    const float* wrow = W1 + d * HID + h * DD;
    const float* av = al + h * DD;
    const float* bv = ar + h * DD;
    float s1 = 0.f, s2 = 0.f;
    for (int c = 0; c < DD; ++c) { s1 += wrow[c] * av[c]; s2 += wrow[c] * bv[c]; }
    wal[d * 4 + h] = s1;
    war[d * 4 + h] = s2;
}

// ---------------- el1/er1 from raw feats (reassociated: feats @ wal1) ---------
__global__ __launch_bounds__(256) void elr1_kernel(
    const float* __restrict__ feats, const float* __restrict__ wal,
    const float* __restrict__ war, float* __restrict__ el, float* __restrict__ er)
{
    int idx = blockIdx.x * 256 + threadIdx.x;   // (n,h)
    if (idx >= NN * HH) return;
    int n = idx >> 2, h = idx & 3;
    const float* f = feats + (size_t)n * INF_;
    float s1 = 0.f, s2 = 0.f;
    #pragma unroll 4
    for (int d = 0; d < INF_; d += 4) {
        float4 fv = *reinterpret_cast<const float4*>(f + d);
        s1 += fv.x * wal[(d + 0) * 4 + h] + fv.y * wal[(d + 1) * 4 + h]
            + fv.z * wal[(d + 2) * 4 + h] + fv.w * wal[(d + 3) * 4 + h];
        s2 += fv.x * war[(d + 0) * 4 + h] + fv.y * war[(d + 1) * 4 + h]
            + fv.z * war[(d + 2) * 4 + h] + fv.w * war[(d + 3) * 4 + h];
    }
    el[idx] = s1;
    er[idx] = s2;
}

// ---------------- layer-1 aggregate over RAW feats (reassociation) ------------
// X1 = (sum alpha*feats) @ W1 : gather 256B feats rows (25.6MB working set vs
// 102MB of F1 rows -> per-XCD L2 multiplicity applies to 4x fewer bytes).
// Wave per dst node; lane l holds feats[.][l]; 4 per-head accumulators.
// Y1 layout: [t][h*64+d], normalized (invden applied) -> feeds per-head GEMM.
__global__ __launch_bounds__(256) void aggregate_feats_kernel(
    const float* __restrict__ feats, const float* __restrict__ w,
    const float* __restrict__ invden, const int* __restrict__ rowptr,
    const int* __restrict__ colsrc, float* __restrict__ Y1)
{
    int t = blockIdx.x * 4 + (threadIdx.x >> 6);
    int lane = threadIdx.x & 63;
    if (t >= NN) return;
    int beg = rowptr[t], end = rowptr[t + 1];
    float a0 = 0.f, a1 = 0.f, a2 = 0.f, a3 = 0.f;
    float b0 = 0.f, b1 = 0.f, b2 = 0.f, b3 = 0.f;
    int i = beg;
    for (; i + 1 < end; i += 2) {
        int s0 = colsrc[i], s1 = colsrc[i + 1];
        float4 w0 = *reinterpret_cast<const float4*>(w + (size_t)i * 4);
        float4 w1 = *reinterpret_cast<const float4*>(w + (size_t)(i + 1) * 4);
        float f0 = feats[(size_t)s0 * INF_ + lane];
        float f1 = feats[(size_t)s1 * INF_ + lane];
        a0 += w0.x * f0; a1 += w0.y * f0; a2 += w0.z * f0; a3 += w0.w * f0;
        b0 += w1.x * f1; b1 += w1.y * f1; b2 += w1.z * f1; b3 += w1.w * f1;
    }
    if (i < end) {
        int s0 = colsrc[i];
        float4 w0 = *reinterpret_cast<const float4*>(w + (size_t)i * 4);
        float f0 = feats[(size_t)s0 * INF_ + lane];
        a0 += w0.x * f0; a1 += w0.y * f0; a2 += w0.z * f0; a3 += w0.w * f0;
    }
    float4 inv = *reinterpret_cast<const float4*>(invden + (size_t)t * 4);
    float* y = Y1 + (size_t)t * HID;
    y[lane]       = (a0 + b0) * inv.x;
    y[64 + lane]  = (a1 + b1) * inv.y;
    y[128 + lane] = (a2 + b2) * inv.z;
    y[192 + lane] = (a3 + b3) * inv.w;
}

// ---------------- per-head GEMM: X1 = relu(Y1 @ W1 + b1) ----------------------
// 4 independent 64x64 GEMMs (one per head). Grid N/128; wave w = head w:
// 128 rows x 64 cols, K=64. No LDS: A frags (f32, split hi/lo in-register,
// 3 MFMAs — X1 feeds layer-2 logits, keep split-split) and B frags (BT1 hi/lo,
// L2-resident 16KB) load straight from global.
__global__ __launch_bounds__(256) void gemm_head_kernel(
    const float* __restrict__ Y1, const u16* __restrict__ BThi,
    const u16* __restrict__ BTlo, const float* __restrict__ bias,
    float* __restrict__ X1, int M)
{
    const int tid  = threadIdx.x;
    const int wv   = tid >> 6, lane = tid & 63;
    const int quad = lane >> 4, l15 = lane & 15;
    const int r0 = blockIdx.x * 128;
    const int cbase = wv * 64;           // head wv's column block

    f32x4 acc[8][4];
    #pragma unroll
    for (int i = 0; i < 8; ++i)
        #pragma unroll
        for (int j = 0; j < 4; ++j)
            acc[i][j] = (f32x4){0.f, 0.f, 0.f, 0.f};

    #pragma unroll
    for (int k0 = 0; k0 < 64; k0 += 32) {
        bf16x8 bh[4], bl[4];
        #pragma unroll
        for (int j = 0; j < 4; ++j) {
            int n = cbase + j * 16 + l15;
            bh[j] = *reinterpret_cast<const bf16x8*>(BThi + (size_t)n * 64 + k0 + quad * 8);
            bl[j] = *reinterpret_cast<const bf16x8*>(BTlo + (size_t)n * 64 + k0 + quad * 8);
        }
        #pragma unroll
        for (int i = 0; i < 8; ++i) {
            int gr = min(r0 + i * 16 + l15, M - 1);
            const float* ap = Y1 + (size_t)gr * HID + cbase + k0 + quad * 8;
            float4 va0 = *reinterpret_cast<const float4*>(ap);
            float4 va1 = *reinterpret_cast<const float4*>(ap + 4);
            float av[8] = {va0.x, va0.y, va0.z, va0.w, va1.x, va1.y, va1.z, va1.w};
            bf16x8 vh, vl;
            #pragma unroll
            for (int m = 0; m < 8; ++m) {
                u16 h = f2bf(av[m]);
                vh[m] = (short)h;
                vl[m] = (short)f2bf(av[m] - bf2f(h));
            }
            #pragma unroll
            for (int j = 0; j < 4; ++j) {
                acc[i][j] = __builtin_amdgcn_mfma_f32_16x16x32_bf16(vh, bh[j], acc[i][j], 0, 0, 0);
                acc[i][j] = __builtin_amdgcn_mfma_f32_16x16x32_bf16(vl, bh[j], acc[i][j], 0, 0, 0);
                acc[i][j] = __builtin_amdgcn_mfma_f32_16x16x32_bf16(vh, bl[j], acc[i][j], 0, 0, 0);
            }
        }
    }
    // C/D layout: col = cbase + j*16 + l15, row = r0 + i*16 + quad*4 + rr
    float bv[4];
    #pragma unroll
    for (int j = 0; j < 4; ++j) bv[j] = bias[cbase + j * 16 + l15];
    #pragma unroll
    for (int i = 0; i < 8; ++i)
        #pragma unroll
        for (int rr = 0; rr < 4; ++rr) {
            int grow = r0 + i * 16 + quad * 4 + rr;
            if (grow < M) {
                float* xrow = X1 + (size_t)grow * HID + cbase + l15;
                #pragma unroll
                for (int j = 0; j < 4; ++j)
                    xrow[j * 16] = fmaxf(acc[i][j][rr] + bv[j], 0.f);
            }
        }
}

// ---------------- MFMA GEMM (layer 2), split-split, fused el/er epilogue ------
// Unchanged from round 8. A=X1 f32 split in-register (3 MFMAs: logits depend
// on this — single-bf16 failed rounds 4/5 at absmax 130). el2/er2 from f32
// accumulators; C stored bf16 (feeds message gather only).
template<bool BF16_OUT>
__global__ __launch_bounds__(256) void mfma_gemm_kernel(
    const float* __restrict__ A, const u16* __restrict__ BThi,
    const u16* __restrict__ BTlo, float* __restrict__ Cf, u16* __restrict__ Cb,
    const float* __restrict__ al, const float* __restrict__ ar,
    float* __restrict__ el, float* __restrict__ er, int M, int K)
{
    __shared__ __align__(16) u16 Ah[128 * 40];
    __shared__ __align__(16) u16 Al[128 * 40];
    __shared__ __align__(16) u16 Bh[128 * 40];
    __shared__ __align__(16) u16 Bl[128 * 40];
    const int tid  = threadIdx.x;
    const int wave = tid >> 6, lane = tid & 63;
    const int quad = lane >> 4, l15 = lane & 15;
    const int wy = wave >> 1, wx = wave & 1;
    const int r0 = blockIdx.x * 128, c0 = blockIdx.y * 128;
    const int sr = tid >> 2, sseg = tid & 3;

    f32x4 acc[4][4];
    #pragma unroll
    for (int i = 0; i < 4; ++i)
        #pragma unroll
        for (int j = 0; j < 4; ++j)
            acc[i][j] = (f32x4){0.f, 0.f, 0.f, 0.f};

    for (int k0 = 0; k0 < K; k0 += 32) {
        #pragma unroll
        for (int half = 0; half < 2; ++half) {
            int r = sr + half * 64;
            int gr = min(r0 + r, M - 1);
            const float* ap = A + (size_t)gr * K + k0 + sseg * 8;
            float4 va0 = *reinterpret_cast<const float4*>(ap);
            float4 va1 = *reinterpret_cast<const float4*>(ap + 4);
            float av[8] = {va0.x, va0.y, va0.z, va0.w, va1.x, va1.y, va1.z, va1.w};
            bf16x8 vh, vl;
            #pragma unroll
            for (int m = 0; m < 8; ++m) {
                u16 h = f2bf(av[m]);
                vh[m] = (short)h;
                vl[m] = (short)f2bf(av[m] - bf2f(h));
            }
            *reinterpret_cast<bf16x8*>(&Ah[r * 40 + sseg * 8]) = vh;
            *reinterpret_cast<bf16x8*>(&Al[r * 40 + sseg * 8]) = vl;
            int gc = c0 + r;   // < 256 always
            *reinterpret_cast<bf16x8*>(&Bh[r * 40 + sseg * 8]) =
                *reinterpret_cast<const bf16x8*>(BThi + (size_t)gc * K + k0 + sseg * 8);
            *reinterpret_cast<bf16x8*>(&Bl[r * 40 + sseg * 8]) =
                *reinterpret_cast<const bf16x8*>(BTlo + (size_t)gc * K + k0 + sseg * 8);
        }
        __syncthreads();
        bf16x8 afh[4], afl[4], bfh[4], bfl[4];
        #pragma unroll
        for (int i = 0; i < 4; ++i) {
            int row = (wy * 64 + i * 16 + l15) * 40 + quad * 8;
            afh[i] = *reinterpret_cast<const bf16x8*>(&Ah[row]);
            afl[i] = *reinterpret_cast<const bf16x8*>(&Al[row]);
        }
        #pragma unroll
        for (int j = 0; j < 4; ++j) {
            int row = (wx * 64 + j * 16 + l15) * 40 + quad * 8;
            bfh[j] = *reinterpret_cast<const bf16x8*>(&Bh[row]);
            bfl[j] = *reinterpret_cast<const bf16x8*>(&Bl[row]);
        }
        #pragma unroll
        for (int i = 0; i < 4; ++i)
            #pragma unroll
            for (int j = 0; j < 4; ++j) {
                acc[i][j] = __builtin_amdgcn_mfma_f32_16x16x32_bf16(afh[i], bfh[j], acc[i][j], 0, 0, 0);
                acc[i][j] = __builtin_amdgcn_mfma_f32_16x16x32_bf16(afl[i], bfh[j], acc[i][j], 0, 0, 0);
                acc[i][j] = __builtin_amdgcn_mfma_f32_16x16x32_bf16(afh[i], bfl[j], acc[i][j], 0, 0, 0);
            }
        __syncthreads();
    }

    // ---- C store. C/D layout: col = l15, row = quad*4 + rr ----
    #pragma unroll
    for (int i = 0; i < 4; ++i)
        #pragma unroll
        for (int rr = 0; rr < 4; ++rr) {
            int grow = r0 + wy * 64 + i * 16 + quad * 4 + rr;
            if (grow < M) {
                if (BF16_OUT) {
                    u16* crow = Cb + (size_t)grow * HID + c0 + wx * 64 + l15;
                    #pragma unroll
                    for (int j = 0; j < 4; ++j) crow[j * 16] = f2bf(acc[i][j][rr]);
                } else {
                    float* crow = Cf + (size_t)grow * HID + c0 + wx * 64 + l15;
                    #pragma unroll
                    for (int j = 0; j < 4; ++j) crow[j * 16] = acc[i][j][rr];
                }
            }
        }

    // ---- fused el/er from f32 accumulators (one head per wave) ----
    const int h = blockIdx.y * 2 + wx;
    float alf[4], arf[4];
    #pragma unroll
    for (int j = 0; j < 4; ++j) {
        alf[j] = al[h * DD + j * 16 + l15];
        arf[j] = ar[h * DD + j * 16 + l15];
    }
    #pragma unroll
    for (int i = 0; i < 4; ++i)
        #pragma unroll
        for (int rr = 0; rr < 4; ++rr) {
            float sl = acc[i][0][rr] * alf[0] + acc[i][1][rr] * alf[1]
                     + acc[i][2][rr] * alf[2] + acc[i][3][rr] * alf[3];
            float sr_ = acc[i][0][rr] * arf[0] + acc[i][1][rr] * arf[1]
                      + acc[i][2][rr] * arf[2] + acc[i][3][rr] * arf[3];
            #pragma unroll
            for (int off = 1; off < 16; off <<= 1) {
                sl  += __shfl_xor(sl, off, 64);
                sr_ += __shfl_xor(sr_, off, 64);
            }
            if (l15 == 0) {
                int grow = r0 + wy * 64 + i * 16 + quad * 4 + rr;
                if (grow < M) {
                    el[grow * 4 + h] = sl;
                    er[grow * 4 + h] = sr_;
                }
            }
        }
}

__device__ __forceinline__ float leaky02(float x) { return x > 0.f ? x : 0.2f * x; }

// ---------------- edge softmax: one thread per (dst-node, head) ----------------
__global__ __launch_bounds__(256) void edge_softmax_kernel(
    const float* __restrict__ el, const float* __restrict__ er,
    const int* __restrict__ rowptr, const int* __restrict__ colsrc,
    float* __restrict__ w, float* __restrict__ invden)
{
    int idx = blockIdx.x * 256 + threadIdx.x;   // (t,h)
    if (idx >= NN * HH) return;
    int t = idx >> 2, h = idx & 3;
    int beg = rowptr[t], end = rowptr[t + 1];
    float ert = er[idx];
    float m = -1e30f;
    for (int i = beg; i < end; ++i) {
        int s = colsrc[i];
        m = fmaxf(m, leaky02(el[s * 4 + h] + ert));
    }
    float den = 0.f;
    for (int i = beg; i < end; ++i) {
        int s = colsrc[i];
        float v = expf(leaky02(el[s * 4 + h] + ert) - m);
        w[(size_t)i * 4 + h] = v;
        den += v;
    }
    invden[idx] = 1.f / den;   // deg >= 1 (self-loops), den > 0
}

// ---------------- layer-2 aggregate: bf16 gather -> bf16 out ------------------
__global__ __launch_bounds__(256) void aggregate_bf16_kernel(
    const u16* __restrict__ F, const float* __restrict__ w,
    const float* __restrict__ invden, const int* __restrict__ rowptr,
    const int* __restrict__ colsrc, const float* __restrict__ bias,
    u16* __restrict__ out)
{
    int t = blockIdx.x * 4 + (threadIdx.x >> 6);
    int lane = threadIdx.x & 63;
    if (t >= NN) return;
    int beg = rowptr[t], end = rowptr[t + 1];
    const int h = lane >> 4;
    float4 acc0 = make_float4(0.f, 0.f, 0.f, 0.f);
    float4 acc1 = make_float4(0.f, 0.f, 0.f, 0.f);
    int i = beg;
    for (; i + 1 < end; i += 2) {
        int s0 = colsrc[i], s1 = colsrc[i + 1];
        float w0 = w[(size_t)i * 4 + h];
        float w1 = w[(size_t)(i + 1) * 4 + h];
        ushort4 f0 = *reinterpret_cast<const ushort4*>(F + (size_t)s0 * HID + 4 * lane);
        ushort4 f1 = *reinterpret_cast<const ushort4*>(F + (size_t)s1 * HID + 4 * lane);
        acc0.x += w0 * bf2f(f0.x); acc0.y += w0 * bf2f(f0.y);
        acc0.z += w0 * bf2f(f0.z); acc0.w += w0 * bf2f(f0.w);
        acc1.x += w1 * bf2f(f1.x); acc1.y += w1 * bf2f(f1.y);
        acc1.z += w1 * bf2f(f1.z); acc1.w += w1 * bf2f(f1.w);
    }
    if (i < end) {
        int s0 = colsrc[i];
        float w0 = w[(size_t)i * 4 + h];
        ushort4 f0 = *reinterpret_cast<const ushort4*>(F + (size_t)s0 * HID + 4 * lane);
        acc0.x += w0 * bf2f(f0.x); acc0.y += w0 * bf2f(f0.y);
        acc0.z += w0 * bf2f(f0.z); acc0.w += w0 * bf2f(f0.w);
    }
    float inv = invden[t * 4 + h];
    float4 bv = *reinterpret_cast<const float4*>(bias + 4 * lane);
    ushort4 r;
    r.x = f2bf(fmaxf((acc0.x + acc1.x) * inv + bv.x, 0.f));
    r.y = f2bf(fmaxf((acc0.y + acc1.y) * inv + bv.y, 0.f));
    r.z = f2bf(fmaxf((acc0.z + acc1.z) * inv + bv.z, 0.f));
    r.w = f2bf(fmaxf((acc0.w + acc1.w) * inv + bv.w, 0.f));
    *reinterpret_cast<ushort4*>(out + (size_t)t * HID + 4 * lane) = r;
}

// ---------------- weighted-average readout (bf16 X): one wave per graph -------
__global__ __launch_bounds__(256) void readout_kernel(
    const u16* __restrict__ X, const float* __restrict__ Ws,
    const float* __restrict__ bs, const int* __restrict__ gptr,
    float* __restrict__ emb)
{
    int g = blockIdx.x * 4 + (threadIdx.x >> 6);
    int lane = threadIdx.x & 63;
    if (g >= GG) return;
    int beg = gptr[g], end = gptr[g + 1];
    float4 wv = *reinterpret_cast<const float4*>(Ws + 4 * lane);
    float b = bs[0];
    float4 acc = make_float4(0.f, 0.f, 0.f, 0.f);
    float wsum = 0.f;
    for (int n = beg; n < end; ++n) {
        ushort4 xv = *reinterpret_cast<const ushort4*>(X + (size_t)n * HID + 4 * lane);
        float x0 = bf2f(xv.x), x1 = bf2f(xv.y), x2 = bf2f(xv.z), x3 = bf2f(xv.w);
        float p = x0 * wv.x + x1 * wv.y + x2 * wv.z + x3 * wv.w;
        #pragma unroll
        for (int off = 32; off; off >>= 1) p += __shfl_xor(p, off, 64);
        float w = 1.f / (1.f + expf(-(p + b)));
        wsum += w;
        acc.x += w * x0; acc.y += w * x1; acc.z += w * x2; acc.w += w * x3;
    }
    float inv = (wsum == 0.f) ? 1.f : wsum;
    float4 e;
    e.x = acc.x / inv; e.y = acc.y / inv; e.z = acc.z / inv; e.w = acc.w / inv;
    *reinterpret_cast<float4*>(emb + (size_t)g * HID + 4 * lane) = e;
}

__device__ __forceinline__ float selu_f(float x)
{
    const float scale = 1.0507009873554805f, alpha = 1.6732632423543772f;
    return scale * (x > 0.f ? x : alpha * expm1f(x));
}

// ---------------- MLP head: one block (128 thr) per graph ----------------
__global__ __launch_bounds__(128) void mlp_kernel(
    const float* __restrict__ emb, const float* __restrict__ fg,
    const float* __restrict__ Wm1, const float* __restrict__ bm1,
    const float* __restrict__ Wm2, const float* __restrict__ bm2,
    const float* __restrict__ Wm3, const float* __restrict__ bm3,
    float* __restrict__ out)
{
    int g = blockIdx.x;
    __shared__ float h[HID + EXTRA];
    __shared__ float h1[128];
    __shared__ float h2[64];
    int tid = threadIdx.x;
    h[tid] = emb[(size_t)g * HID + tid];
    h[128 + tid] = emb[(size_t)g * HID + 128 + tid];
    if (tid < EXTRA) h[HID + tid] = fg[(size_t)g * EXTRA + tid];
    __syncthreads();
    float acc = bm1[tid];
    for (int i = 0; i < HID + EXTRA; ++i) acc += h[i] * Wm1[i * 128 + tid];
    h1[tid] = selu_f(acc);
    __syncthreads();
    if (tid < 64) {
        float acc2 = bm2[tid];
        for (int i = 0; i < 128; ++i) acc2 += h1[i] * Wm2[i * 64 + tid];
        h2[tid] = selu_f(acc2);
    }
    __syncthreads();
    if (tid < 64) {
        float p = h2[tid] * Wm3[tid];
        #pragma unroll
        for (int off = 32; off; off >>= 1) p += __shfl_xor(p, off, 64);
        if (tid == 0) out[g] = p + bm3[0];
    }
}

// ---------------- CSR build helpers ----------------
__global__ void count_dst_kernel(const int* __restrict__ dst, int* __restrict__ cnt, int E)
{
    int e = blockIdx.x * 256 + threadIdx.x;
    if (e < E) atomicAdd(&cnt[dst[e]], 1);
}
__global__ void count_gid_kernel(const int* __restrict__ gid, int* __restrict__ cnt, int n)
{
    int i = blockIdx.x * 256 + threadIdx.x;
    if (i < n) atomicAdd(&cnt[gid[i]], 1);
}
__global__ void fill_csr_kernel(const int* __restrict__ src, const int* __restrict__ dst,
                                int* __restrict__ cursor, int* __restrict__ colsrc, int E)
{
    int e = blockIdx.x * 256 + threadIdx.x;
    if (e < E) {
        int p = atomicAdd(&cursor[dst[e]], 1);
        colsrc[p] = src[e];
    }
}

// exclusive scan, 1024 elems/block
__global__ __launch_bounds__(256) void scan_blocks_kernel(
    const int* __restrict__ in, int n, int* __restrict__ out, int* __restrict__ partials)
{
    __shared__ int lds[256];
    int tid = threadIdx.x;
    int base = blockIdx.x * 1024 + tid * 4;
    int v0 = (base + 0 < n) ? in[base + 0] : 0;
    int v1 = (base + 1 < n) ? in[base + 1] : 0;
    int v2 = (base + 2 < n) ? in[base + 2] : 0;
    int v3 = (base + 3 < n) ? in[base + 3] : 0;
    int s = v0 + v1 + v2 + v3;
    lds[tid] = s;
    __syncthreads();
    for (int off = 1; off < 256; off <<= 1) {
        int t = (tid >= off) ? lds[tid - off] : 0;
        __syncthreads();
        lds[tid] += t;
        __syncthreads();
    }
    int excl = lds[tid] - s;
    if (base + 0 < n) out[base + 0] = excl;
    if (base + 1 < n) out[base + 1] = excl + v0;
    if (base + 2 < n) out[base + 2] = excl + v0 + v1;
    if (base + 3 < n) out[base + 3] = excl + v0 + v1 + v2;
    if (tid == 255) partials[blockIdx.x] = lds[255];
}

__global__ __launch_bounds__(256) void scan_partials_kernel(int* partials, int nb)
{
    __shared__ int lds[256];
    int tid = threadIdx.x;
    int v = (tid < nb) ? partials[tid] : 0;
    lds[tid] = v;
    __syncthreads();
    for (int off = 1; off < 256; off <<= 1) {
        int t = (tid >= off) ? lds[tid - off] : 0;
        __syncthreads();
        lds[tid] += t;
        __syncthreads();
    }
    int excl = lds[tid] - v;
    if (tid < nb) partials[tid] = excl;
}

__global__ void add_offsets_kernel(int* __restrict__ out, const int* __restrict__ partials, int n)
{
    int i = blockIdx.x * 256 + threadIdx.x;
    if (i < n) out[i] += partials[i >> 10];
}

// ---------------- launch ----------------
extern "C" void kernel_launch(void* const* d_in, const int* in_sizes, int n_in,
                              void* d_out, int out_size, void* d_ws, size_t ws_size,
                              hipStream_t stream)
{
    const float* feats_node  = (const float*)d_in[0];
    const float* feats_graph = (const float*)d_in[1];
    const float* W1  = (const float*)d_in[2];
    const float* al1 = (const float*)d_in[3];
    const float* ar1 = (const float*)d_in[4];
    const float* b1  = (const float*)d_in[5];
    const float* W2  = (const float*)d_in[6];
    const float* al2 = (const float*)d_in[7];
    const float* ar2 = (const float*)d_in[8];
    const float* b2  = (const float*)d_in[9];
    const float* Ws  = (const float*)d_in[10];
    const float* bs  = (const float*)d_in[11];
    const float* Wm1 = (const float*)d_in[12];
    const float* bm1 = (const float*)d_in[13];
    const float* Wm2 = (const float*)d_in[14];
    const float* bm2 = (const float*)d_in[15];
    const float* Wm3 = (const float*)d_in[16];
    const float* bm3 = (const float*)d_in[17];
    const int* src = (const int*)d_in[18];
    const int* dst = (const int*)d_in[19];
    const int* gid = (const int*)d_in[20];
    float* out = (float*)d_out;
    const int E = in_sizes[18];   // 900000

    // workspace carve-up (256B aligned). Total ~230.8 MB = proven footprint.
    char* p = (char*)d_ws;
    auto alloc = [&](size_t bytes) {
        char* r = p;
        p += (bytes + 255) & ~(size_t)255;
        return r;
    };
    float* Y1     = (float*)alloc((size_t)NN * HID * 4);    // Y1 f32; later F2 bf16 (alias)
    float* X      = (float*)alloc((size_t)NN * HID * 4);    // X1 f32; later X2 bf16 (alias)
    float* el     = (float*)alloc((size_t)NN * HH * 4);
    float* er     = (float*)alloc((size_t)NN * HH * 4);
    float* wbuf   = (float*)alloc((size_t)E * HH * 4);      // 14.4 MB
    float* invden = (float*)alloc((size_t)NN * HH * 4);
    int*   cnt    = (int*)alloc((size_t)(NN + 1) * 4);      // reused as cursor
    int*   rowptr = (int*)alloc((size_t)(NN + 1) * 4);
    int*   colsrc = (int*)alloc((size_t)E * 4);
    int*   gcnt   = (int*)alloc((size_t)(GG + 1) * 4);
    int*   gptr   = (int*)alloc((size_t)(GG + 1) * 4);
    int*   parts  = (int*)alloc(1024 * 4);
    float* emb    = (float*)alloc((size_t)GG * HID * 4);
    u16*   BT1h   = (u16*)alloc((size_t)HID * INF_ * 2);
    u16*   BT1l   = (u16*)alloc((size_t)HID * INF_ * 2);
    u16*   BT2h   = (u16*)alloc((size_t)HID * HID * 2);
    u16*   BT2l   = (u16*)alloc((size_t)HID * HID * 2);
    float* wal1   = (float*)alloc(INF_ * HH * 4);
    float* war1   = (float*)alloc(INF_ * HH * 4);
    u16*   Fbf2   = (u16*)Y1;  // alias: Y1 dead after gemm_head
    u16*   Xbf2   = (u16*)X;   // alias: X1 dead after gemm2 consumed it

    // ---- CSR over dst ----
    hipMemsetAsync(cnt, 0, (size_t)(NN + 1) * 4, stream);
    count_dst_kernel<<<(E + 255) / 256, 256, 0, stream>>>(dst, cnt, E);
    {
        int n = NN + 1, nb = (n + 1023) / 1024;
        scan_blocks_kernel<<<nb, 256, 0, stream>>>(cnt, n, rowptr, parts);
        scan_partials_kernel<<<1, 256, 0, stream>>>(parts, nb);
        add_offsets_kernel<<<(n + 255) / 256, 256, 0, stream>>>(rowptr, parts, n);
    }
    hipMemcpyAsync(cnt, rowptr, (size_t)(NN + 1) * 4, hipMemcpyDeviceToDevice, stream);
    fill_csr_kernel<<<(E + 255) / 256, 256, 0, stream>>>(src, dst, cnt, colsrc, E);

    // ---- graph ranges (node_gid is sorted) ----
    hipMemsetAsync(gcnt, 0, (size_t)(GG + 1) * 4, stream);
    count_gid_kernel<<<(NN + 255) / 256, 256, 0, stream>>>(gid, gcnt, NN);
    {
        int n = GG + 1, nb = (n + 1023) / 1024;
        scan_blocks_kernel<<<nb, 256, 0, stream>>>(gcnt, n, gptr, parts);
        scan_partials_kernel<<<1, 256, 0, stream>>>(parts, nb);
        add_offsets_kernel<<<(n + 255) / 256, 256, 0, stream>>>(gptr, parts, n);
    }

    // ---- weight conversions / precomputes ----
    wsplit_kernel<<<(HID * INF_ + 255) / 256, 256, 0, stream>>>(W1, BT1h, BT1l, INF_, 6);
    wsplit_kernel<<<(HID * HID + 255) / 256, 256, 0, stream>>>(W2, BT2h, BT2l, HID, 8);
    walprep_kernel<<<1, 256, 0, stream>>>(W1, al1, ar1, wal1, war1);

    const int nh_blocks = (NN * HH + 255) / 256;

    // ---- GAT layer 1 (reassociated: gather raw feats, then per-head GEMM) ----
    elr1_kernel<<<nh_blocks, 256, 0, stream>>>(feats_node, wal1, war1, el, er);
    edge_softmax_kernel<<<nh_blocks, 256, 0, stream>>>(el, er, rowptr, colsrc, wbuf, invden);
    aggregate_feats_kernel<<<(NN + 3) / 4, 256, 0, stream>>>(feats_node, wbuf, invden,
                                                             rowptr, colsrc, Y1);
    gemm_head_kernel<<<(NN + 127) / 128, 256, 0, stream>>>(Y1, BT1h, BT1l, b1, X, NN);

    // ---- GAT layer 2 (unchanged: K=256 GEMM w/ el2/er2 epilogue, bf16 path) --
    dim3 ggrid((NN + 127) / 128, HID / 128);
    mfma_gemm_kernel<true><<<ggrid, 256, 0, stream>>>(
        X, BT2h, BT2l, nullptr, Fbf2, al2, ar2, el, er, NN, HID);
    edge_softmax_kernel<<<nh_blocks, 256, 0, stream>>>(el, er, rowptr, colsrc, wbuf, invden);
    aggregate_bf16_kernel<<<(NN + 3) / 4, 256, 0, stream>>>(Fbf2, wbuf, invden, rowptr, colsrc,
                                                            b2, Xbf2);

    // ---- readout + MLP ----
    readout_kernel<<<(GG + 3) / 4, 256, 0, stream>>>(Xbf2, Ws, bs, gptr, emb);
    mlp_kernel<<<GG, 128, 0, stream>>>(emb, feats_graph, Wm1, bm1, Wm2, bm2, Wm3, bm3, out);
}